// Round 3
// baseline (2411.195 us; speedup 1.0000x reference)
//
#include <hip/hip_runtime.h>

// GNNRoIFusion on MI355X (gfx950).
// B=2, H=W=128, C=256, HEADS=4, D=64, M=3, P=32768 pixels.
// Round 3: runtime input-dtype detection (fp32 vs bf16) + chunked pipeline
// (ws ~58 MiB). Internals bf16, params fp32, fp32 accumulate.

#define Pn 32768
#define CPIX 4096   // pixels per chunk
#define NCH 8

typedef __attribute__((ext_vector_type(8))) short bf16x8;
typedef __attribute__((ext_vector_type(4))) float f32x4;

__device__ __forceinline__ float b2f(short s) {
  unsigned u = ((unsigned)(unsigned short)s) << 16;
  float f;
  __builtin_memcpy(&f, &u, 4);
  return f;
}
__device__ __forceinline__ short f2b(float f) {
  unsigned u;
  __builtin_memcpy(&u, &f, 4);
  u += 0x7fffu + ((u >> 16) & 1u);   // RNE to bf16
  return (short)(u >> 16);
}
__device__ __forceinline__ float ldany(const void* p, int i, int bf) {
  return bf ? b2f(((const short*)p)[i]) : ((const float*)p)[i];
}
__device__ __forceinline__ float wsum(float v) {
#pragma unroll
  for (int m = 1; m < 64; m <<= 1) v += __shfl_xor(v, m, 64);
  return v;
}

// ---------- dtype probe: bf16 data -> even 16b words decode plausibly -------
__global__ __launch_bounds__(256) void detect_dtype(const void* probe, int* flag) {
  const short* s = (const short*)probe;
  int cnt = 0;
#pragma unroll
  for (int i = 0; i < 8; ++i) {
    short v = s[(threadIdx.x * 8 + i) * 2];
    int e = ((unsigned short)v >> 7) & 0xFF;
    cnt += (e >= 100 && e <= 127) ? 1 : 0;   // |v| in [~2^-27, 2)
  }
  __shared__ int tot;
  if (threadIdx.x == 0) tot = 0;
  __syncthreads();
  atomicAdd(&tot, cnt);
  __syncthreads();
  if (threadIdx.x == 0) flag[0] = (tot > 1024) ? 1 : 0;  // 1 = bf16 inputs
}

// ---------- small params -> fp32 block (18 vectors of 256) ------------------
struct P18 { const void* p[18]; };
__global__ __launch_bounds__(256) void prep_params(P18 s, const int* flag, float* pb) {
  int bf = *flag;
  int t = threadIdx.x;
#pragma unroll
  for (int v = 0; v < 18; ++v) pb[v * 256 + t] = ldany(s.p[v], t, bf);
}

// ---------- weight prep: Wt[n][k] = W[k][n] (bf16), 6 weights 256x256 -------
__global__ __launch_bounds__(256) void prep_gemm_w(
    const void* w0, const void* w1, const void* w2, const void* w3,
    const void* w4, const void* w5, const int* flag, short* wt) {
  int bf = *flag;
  const void* src;
  switch (blockIdx.y) {
    case 0: src = w0; break;
    case 1: src = w1; break;
    case 2: src = w2; break;
    case 3: src = w3; break;
    case 4: src = w4; break;
    default: src = w5; break;
  }
  int idx = blockIdx.x * 256 + threadIdx.x;     // n*256 + k
  int n = idx >> 8, k = idx & 255;
  wt[blockIdx.y * 65536 + idx] = f2b(ldany(src, k * 256 + n, bf));
}

// conv_w [cout][cin][3][3] -> cwt[tap][cout][cin] (bf16)
__global__ __launch_bounds__(256) void prep_conv_w(const void* cw, const int* flag,
                                                   short* cwt) {
  int bf = *flag;
  int idx = blockIdx.x * 256 + threadIdx.x;     // tap*65536 + n*256 + k
  int tap = idx >> 16;
  int n = (idx >> 8) & 255;
  int k = idx & 255;
  cwt[idx] = f2b(ldany(cw, (n * 256 + k) * 9 + tap, bf));
}

// ---------- gather one chunk: modal [B,C,H,W] -> Xc nodes 1..3 + MEANc ------
__global__ __launch_bounds__(256) void gather_chunk(
    const void* m0, const void* m1, const void* m2, const int* flag,
    short* Xc, short* meanc, int sb0) {
  int bf = *flag;
  int sb = sb0 + blockIdx.x;        // 64-pixel segment: p in [sb*64, sb*64+64)
  int wt = sb & 1, h = (sb >> 1) & 127, b = sb >> 8;
  int w0 = wt * 64;
  int tid = threadIdx.x;
  __shared__ float tile[64][65];
  const void* srcs[3] = {m0, m1, m2};
  int lp0 = blockIdx.x * 64;        // chunk-local pixel base

  for (int cb = 0; cb < 256; cb += 64) {
    float macc[16];
#pragma unroll
    for (int i = 0; i < 16; ++i) macc[i] = 0.f;
#pragma unroll
    for (int m = 0; m < 3; ++m) {
      __syncthreads();
      for (int cc = 0; cc < 16; ++cc) {       // load lanes along w (coalesced)
        int c_l = (tid >> 6) + cc * 4;
        int gidx = ((b * 256 + cb + c_l) * 128 + h) * 128 + w0 + (tid & 63);
        tile[c_l][tid & 63] = ldany(srcs[m], gidx, bf);
      }
      __syncthreads();
      int c_l = tid & 63;
      for (int ww = 0; ww < 16; ++ww) {       // store lanes along c (coalesced)
        int w_l = (tid >> 6) + ww * 4;
        float v = tile[c_l][w_l];
        macc[ww] += v;
        Xc[((lp0 + w_l) * 4 + 1 + m) * 256 + cb + c_l] = f2b(v);
      }
    }
    int c_l = tid & 63;
    for (int ww = 0; ww < 16; ++ww) {
      int w_l = (tid >> 6) + ww * 4;
      meanc[(lp0 + w_l) * 256 + cb + c_l] = f2b(macc[ww] * (1.f / 3.f));
    }
  }
}

// ---------- GEMM: out[row*ostride+n] = A[M,256] @ Bt[n][k]^T + bias ---------
template <int RELU>
__global__ __launch_bounds__(256) void gemm16(
    const short* __restrict__ A, const short* __restrict__ Bt,
    const float* __restrict__ bias, short* __restrict__ out, int M, int ostride) {
  int lane = threadIdx.x & 63;
  int wave = blockIdx.x * 4 + (threadIdx.x >> 6);
  int rowTile = wave >> 2;
  int cgrp = wave & 3;
  int row0 = rowTile * 16;
  if (row0 >= M) return;
  int r = lane & 15, q = lane >> 4;
  const short* aptr = A + (row0 + r) * 256 + q * 8;
  const short* bptr = Bt + (cgrp * 64 + r) * 256 + q * 8;

  f32x4 acc[4];
#pragma unroll
  for (int c = 0; c < 4; ++c) acc[c] = (f32x4){0.f, 0.f, 0.f, 0.f};

#pragma unroll
  for (int k0 = 0; k0 < 256; k0 += 32) {
    bf16x8 a = *(const bf16x8*)(aptr + k0);
#pragma unroll
    for (int c = 0; c < 4; ++c) {
      bf16x8 bb = *(const bf16x8*)(bptr + c * 16 * 256 + k0);
      acc[c] = __builtin_amdgcn_mfma_f32_16x16x32_bf16(a, bb, acc[c], 0, 0, 0);
    }
  }
#pragma unroll
  for (int c = 0; c < 4; ++c) {
    int n = cgrp * 64 + c * 16 + r;
    float bs = bias[n];
#pragma unroll
    for (int i = 0; i < 4; ++i) {
      float v = acc[c][i] + bs;
      if (RELU) v = fmaxf(v, 0.f);
      out[(row0 + q * 4 + i) * ostride + n] = f2b(v);
    }
  }
}

// ---------- per-pixel GATv2 + residual + layernorm (chunk-local) ------------
__global__ __launch_bounds__(256) void attn_ln(
    const short* __restrict__ XLc, const short* __restrict__ XRc,
    const float* __restrict__ att, const float* __restrict__ bias,
    const float* __restrict__ lng, const float* __restrict__ lnb,
    short* __restrict__ Xc, int pOff, short* frows, short* fimgb, int writeFused) {
  int lane = threadIdx.x & 63;                    // lane = d within head
  int lp = blockIdx.x * 4 + (threadIdx.x >> 6);   // chunk-local pixel
  int p = pOff + lp;                              // global pixel
  int lbase = lp * 4 * 256;

  float xl[4][4], xr[4][4], xres[4][4];
#pragma unroll
  for (int i = 0; i < 4; ++i)
#pragma unroll
    for (int h = 0; h < 4; ++h) {
      int off = lbase + i * 256 + h * 64 + lane;
      xl[i][h] = b2f(XLc[off]);
      xr[i][h] = b2f(XRc[off]);
      xres[i][h] = b2f(Xc[off]);
    }
  float attr[4], biasr[4], gr[4], br[4];
#pragma unroll
  for (int h = 0; h < 4; ++h) {
    attr[h] = att[h * 64 + lane];
    biasr[h] = bias[h * 64 + lane];
    gr[h] = lng[h * 64 + lane];
    br[h] = lnb[h * 64 + lane];
  }

  float outv[4][4];
#pragma unroll
  for (int i = 0; i < 4; ++i) {
#pragma unroll
    for (int h = 0; h < 4; ++h) {
      float s[4];
#pragma unroll
      for (int j = 0; j < 4; ++j) {
        float t = xr[i][h] + xl[j][h];
        t = fmaxf(t, 0.f) + 0.2f * fminf(t, 0.f);   // leaky_relu 0.2
        s[j] = wsum(t * attr[h]);
      }
      float mx = fmaxf(fmaxf(s[0], s[1]), fmaxf(s[2], s[3]));
      float e0 = expf(s[0] - mx), e1 = expf(s[1] - mx);
      float e2 = expf(s[2] - mx), e3 = expf(s[3] - mx);
      float inv = 1.f / (e0 + e1 + e2 + e3);
      outv[i][h] = (e0 * xl[0][h] + e1 * xl[1][h] + e2 * xl[2][h] + e3 * xl[3][h]) * inv;
    }
  }
#pragma unroll
  for (int i = 0; i < 4; ++i) {
    float y[4];
#pragma unroll
    for (int h = 0; h < 4; ++h) y[h] = outv[i][h] + biasr[h] + xres[i][h];
    float mu = wsum(y[0] + y[1] + y[2] + y[3]) * (1.f / 256.f);
    float d[4], vs = 0.f;
#pragma unroll
    for (int h = 0; h < 4; ++h) { d[h] = y[h] - mu; vs += d[h] * d[h]; }
    float var = wsum(vs) * (1.f / 256.f);
    float rs = rsqrtf(var + 1e-5f);
#pragma unroll
    for (int h = 0; h < 4; ++h) {
      short ob = f2b(d[h] * rs * gr[h] + br[h]);
      Xc[lbase + i * 256 + h * 64 + lane] = ob;
      if (writeFused && i == 0) {
        int c = h * 64 + lane;
        frows[p * 256 + c] = ob;
        int w = p & 127, hh = (p >> 7) & 127, b = p >> 14;
        fimgb[((b * 256 + c) * 128 + hh) * 128 + w] = ob;
      }
    }
  }
}

// ---------- conv3x3 (9-tap MFMA GEMM) + BN + ReLU + residual ----------------
__global__ __launch_bounds__(256) void conv_bn_res(
    const short* __restrict__ cwt, const short* __restrict__ rows,
    const short* __restrict__ imgb, const float* __restrict__ bnp,
    const int* flag, void* __restrict__ outp) {
  int bf = *flag;
  int lane = threadIdx.x & 63;
  int wave = blockIdx.x * 4 + (threadIdx.x >> 6);
  int pt = wave >> 2;       // 16-pixel tile (never crosses an image row)
  int cg = wave & 3;        // 64-cout group
  int r = lane & 15, q = lane >> 4;
  int p = pt * 16 + r;
  int w = p & 127, h = (p >> 7) & 127, b = p >> 14;

  f32x4 acc[4];
#pragma unroll
  for (int c = 0; c < 4; ++c) acc[c] = (f32x4){0.f, 0.f, 0.f, 0.f};
  bf16x8 bz = {0, 0, 0, 0, 0, 0, 0, 0};

#pragma unroll
  for (int ty = 0; ty < 3; ++ty) {
#pragma unroll
    for (int tx = 0; tx < 3; ++tx) {
      int hh = h + ty - 1, ww = w + tx - 1;
      bool valid = ((unsigned)hh < 128u) && ((unsigned)ww < 128u);
      int srcRow = (b * 128 + hh) * 128 + ww;
      const short* bptr = rows + srcRow * 256 + q * 8;
      const short* aptr = cwt + ((ty * 3 + tx) * 256 + cg * 64 + r) * 256 + q * 8;
#pragma unroll
      for (int k0 = 0; k0 < 256; k0 += 32) {
        bf16x8 bb = bz;
        if (valid) bb = *(const bf16x8*)(bptr + k0);
#pragma unroll
        for (int c = 0; c < 4; ++c) {
          bf16x8 aa = *(const bf16x8*)(aptr + c * 16 * 256 + k0);
          acc[c] = __builtin_amdgcn_mfma_f32_16x16x32_bf16(aa, bb, acc[c], 0, 0, 0);
        }
      }
    }
  }
#pragma unroll
  for (int c = 0; c < 4; ++c) {
#pragma unroll
    for (int i = 0; i < 4; ++i) {
      int n = cg * 64 + c * 16 + q * 4 + i;
      float scale = rsqrtf(bnp[768 + n] + 1e-5f) * bnp[n];
      float v = (acc[c][i] - bnp[512 + n]) * scale + bnp[256 + n];
      v = fmaxf(v, 0.f);
      int idx = ((b * 256 + n) * 128 + h) * 128 + w;
      float res = v + b2f(imgb[idx]);
      if (bf) ((short*)outp)[idx] = f2b(res);
      else    ((float*)outp)[idx] = res;
    }
  }
}

extern "C" void kernel_launch(void* const* d_in, const int* in_sizes, int n_in,
                              void* d_out, int out_size, void* d_ws, size_t ws_size,
                              hipStream_t stream) {
  const void* m0 = d_in[0];
  const void* m1 = d_in[1];
  const void* m2 = d_in[2];

  // ws layout (element offsets in shorts). Total ~58 MiB.
  short* ws = (short*)d_ws;
  short* FROWS = ws;                      //  8,388,608 el
  short* FIMGB = ws + 8388608;            //  8,388,608 el
  short* XLc   = ws + 16777216;           //  4,194,304 el (alias MEANc)
  short* XRc   = ws + 20971520;           //  4,194,304 el (alias H1c)
  short* Xc    = ws + 25165824;           //  4,194,304 el
  short* WT    = ws + 29360128;           //  6 x 65536
  short* CWT   = ws + 29753344;           //  9 x 65536
  float* PB    = (float*)(ws + 30343168); // 18 x 256 fp32
  int*   FLAG  = (int*)(ws + 30352384);

  detect_dtype<<<1, 256, 0, stream>>>(d_in[3], FLAG);

  P18 pp;
  pp.p[0] = d_in[4];   // fn_b1
  pp.p[1] = d_in[6];   // fn_b2
  pp.p[2] = d_in[8];   // l0_bl
  pp.p[3] = d_in[10];  // l0_br
  pp.p[4] = d_in[11];  // l0_att
  pp.p[5] = d_in[12];  // l0_bias
  pp.p[6] = d_in[13];  // ln0_g
  pp.p[7] = d_in[14];  // ln0_b
  pp.p[8] = d_in[16];  // l1_bl
  pp.p[9] = d_in[18];  // l1_br
  pp.p[10] = d_in[19]; // l1_att
  pp.p[11] = d_in[20]; // l1_bias
  pp.p[12] = d_in[21]; // ln1_g
  pp.p[13] = d_in[22]; // ln1_b
  pp.p[14] = d_in[24]; // bn_g
  pp.p[15] = d_in[25]; // bn_b
  pp.p[16] = d_in[26]; // bn_m
  pp.p[17] = d_in[27]; // bn_v
  prep_params<<<1, 256, 0, stream>>>(pp, FLAG, PB);

  prep_gemm_w<<<dim3(256, 6), 256, 0, stream>>>(d_in[3], d_in[5], d_in[7],
                                                d_in[9], d_in[15], d_in[17],
                                                FLAG, WT);
  prep_conv_w<<<2304, 256, 0, stream>>>(d_in[23], FLAG, CWT);

  for (int ci = 0; ci < NCH; ++ci) {
    gather_chunk<<<64, 256, 0, stream>>>(m0, m1, m2, FLAG, Xc, XLc, ci * 64);
    // fusion MLP: MEANc(=XLc) -> H1c(=XRc) -> Xc node 0
    gemm16<1><<<256, 256, 0, stream>>>(XLc, WT + 0 * 65536, PB + 0 * 256, XRc,
                                       CPIX, 256);
    gemm16<0><<<256, 256, 0, stream>>>(XRc, WT + 1 * 65536, PB + 1 * 256, Xc,
                                       CPIX, 1024);
    for (int l = 0; l < 2; ++l) {
      gemm16<0><<<1024, 256, 0, stream>>>(Xc, WT + (2 + 2 * l) * 65536,
                                          PB + (2 + 6 * l) * 256, XLc,
                                          4 * CPIX, 256);
      gemm16<0><<<1024, 256, 0, stream>>>(Xc, WT + (3 + 2 * l) * 65536,
                                          PB + (3 + 6 * l) * 256, XRc,
                                          4 * CPIX, 256);
      attn_ln<<<1024, 256, 0, stream>>>(XLc, XRc, PB + (4 + 6 * l) * 256,
                                        PB + (5 + 6 * l) * 256,
                                        PB + (6 + 6 * l) * 256,
                                        PB + (7 + 6 * l) * 256, Xc, ci * CPIX,
                                        FROWS, FIMGB, l);
    }
  }

  conv_bn_res<<<2048, 256, 0, stream>>>(CWT, FROWS, FIMGB, PB + 14 * 256, FLAG,
                                        d_out);
}

// Round 4
// 1709.126 us; speedup vs baseline: 1.4108x; 1.4108x over previous
//
#include <hip/hip_runtime.h>

// GNNRoIFusion on MI355X (gfx950).
// B=2, H=W=128, C=256, HEADS=4, D=64, M=3, P=32768 pixels.
// Round 4: m97-style LDS-staged tile GEMM (global_load_lds + XOR-swizzle)
// for proj (fused Wl|Wr, N=512), MLP, and conv (9-tap over zero-padded rows).

#define Pn 32768
#define CPIX 4096   // pixels per chunk
#define NCH 8
#define PADR 16900  // 130*130 padded rows per batch

typedef __attribute__((ext_vector_type(8))) short bf16x8;
typedef __attribute__((ext_vector_type(4))) float f32x4;

__device__ __forceinline__ float b2f(short s) {
  unsigned u = ((unsigned)(unsigned short)s) << 16;
  float f;
  __builtin_memcpy(&f, &u, 4);
  return f;
}
__device__ __forceinline__ short f2b(float f) {
  unsigned u;
  __builtin_memcpy(&u, &f, 4);
  u += 0x7fffu + ((u >> 16) & 1u);   // RNE to bf16
  return (short)(u >> 16);
}
__device__ __forceinline__ float ldany(const void* p, int i, int bf) {
  return bf ? b2f(((const short*)p)[i]) : ((const float*)p)[i];
}
__device__ __forceinline__ float wsum(float v) {
#pragma unroll
  for (int m = 1; m < 64; m <<= 1) v += __shfl_xor(v, m, 64);
  return v;
}
// async global->LDS, 16B per lane; lds base wave-uniform, lane i -> base+16i
__device__ __forceinline__ void gload_lds16(const short* g, short* l) {
  __builtin_amdgcn_global_load_lds(
      (const __attribute__((address_space(1))) unsigned int*)g,
      (__attribute__((address_space(3))) unsigned int*)l, 16, 0, 0);
}

// ---------- dtype probe ------------------------------------------------------
__global__ __launch_bounds__(256) void detect_dtype(const void* probe, int* flag) {
  const short* s = (const short*)probe;
  int cnt = 0;
#pragma unroll
  for (int i = 0; i < 8; ++i) {
    short v = s[(threadIdx.x * 8 + i) * 2];
    int e = ((unsigned short)v >> 7) & 0xFF;
    cnt += (e >= 100 && e <= 127) ? 1 : 0;
  }
  __shared__ int tot;
  if (threadIdx.x == 0) tot = 0;
  __syncthreads();
  atomicAdd(&tot, cnt);
  __syncthreads();
  if (threadIdx.x == 0) flag[0] = (tot > 1024) ? 1 : 0;  // 1 = bf16 inputs
}

// ---------- small params -> fp32 block (18 vectors of 256) ------------------
struct P18 { const void* p[18]; };
__global__ __launch_bounds__(256) void prep_params(P18 s, const int* flag, float* pb) {
  int bf = *flag;
  int t = threadIdx.x;
#pragma unroll
  for (int v = 0; v < 18; ++v) pb[v * 256 + t] = ldany(s.p[v], t, bf);
}

// ---------- weight prep: Wt[n][k] = W[k][n] (bf16) --------------------------
__global__ __launch_bounds__(256) void prep_gemm_w(
    const void* w0, const void* w1, const void* w2, const void* w3,
    const void* w4, const void* w5, const int* flag, short* wt) {
  int bf = *flag;
  const void* src;
  switch (blockIdx.y) {
    case 0: src = w0; break;
    case 1: src = w1; break;
    case 2: src = w2; break;
    case 3: src = w3; break;
    case 4: src = w4; break;
    default: src = w5; break;
  }
  int idx = blockIdx.x * 256 + threadIdx.x;     // n*256 + k
  int n = idx >> 8, k = idx & 255;
  wt[blockIdx.y * 65536 + idx] = f2b(ldany(src, k * 256 + n, bf));
}

// conv_w [cout][cin][3][3] -> cwt[tap][cout][cin]
__global__ __launch_bounds__(256) void prep_conv_w(const void* cw, const int* flag,
                                                   short* cwt) {
  int bf = *flag;
  int idx = blockIdx.x * 256 + threadIdx.x;
  int tap = idx >> 16;
  int n = (idx >> 8) & 255;
  int k = idx & 255;
  cwt[idx] = f2b(ldany(cw, (n * 256 + k) * 9 + tap, bf));
}

// ---------- zero the halo of FROWSpad [2][130][130][256] --------------------
__global__ __launch_bounds__(256) void zero_border(short* rowsPad) {
  int id = blockIdx.x;              // 0..1031
  int b = id >= 516;
  int r = id - b * 516;
  int hp, wp;
  if (r < 130)      { hp = 0;       wp = r; }
  else if (r < 260) { hp = 129;     wp = r - 130; }
  else if (r < 388) { hp = r - 259; wp = 0; }
  else              { hp = r - 387; wp = 129; }
  rowsPad[(b * PADR + hp * 130 + wp) * 256 + threadIdx.x] = 0;
}

// ---------- gather chunk: modal [B,C,H,W] -> Xc nodes 1..3 + MEANc ----------
__global__ __launch_bounds__(256) void gather_chunk(
    const void* m0, const void* m1, const void* m2, const int* flag,
    short* Xc, short* meanc, int sb0) {
  int bf = *flag;
  int sb = sb0 + blockIdx.x;        // 64-pixel segment
  int wt = sb & 1, h = (sb >> 1) & 127, b = sb >> 8;
  int w0 = wt * 64;
  int tid = threadIdx.x;
  __shared__ float tile[64][65];
  const void* srcs[3] = {m0, m1, m2};
  int lp0 = blockIdx.x * 64;

  for (int cb = 0; cb < 256; cb += 64) {
    float macc[16];
#pragma unroll
    for (int i = 0; i < 16; ++i) macc[i] = 0.f;
#pragma unroll
    for (int m = 0; m < 3; ++m) {
      __syncthreads();
      for (int cc = 0; cc < 16; ++cc) {
        int c_l = (tid >> 6) + cc * 4;
        int gidx = ((b * 256 + cb + c_l) * 128 + h) * 128 + w0 + (tid & 63);
        tile[c_l][tid & 63] = ldany(srcs[m], gidx, bf);
      }
      __syncthreads();
      int c_l = tid & 63;
      for (int ww = 0; ww < 16; ++ww) {
        int w_l = (tid >> 6) + ww * 4;
        float v = tile[c_l][w_l];
        macc[ww] += v;
        Xc[((lp0 + w_l) * 4 + 1 + m) * 256 + cb + c_l] = f2b(v);
      }
    }
    int c_l = tid & 63;
    for (int ww = 0; ww < 16; ++ww) {
      int w_l = (tid >> 6) + ww * 4;
      meanc[(lp0 + w_l) * 256 + cb + c_l] = f2b(macc[ww] * (1.f / 3.f));
    }
  }
}

// ---------- tiled GEMM: out[m*ostride+n] = A[M,256] @ Bt[n][256]^T + bias ---
// block = 128 rows x 128 cols, 4 waves of 64x64; BK=64, K=256 (4 iters).
// LDS XOR-swizzle: physical 16B-chunk slot = logical_chunk ^ (row & 7).
template <int RELU>
__global__ __launch_bounds__(256) void gemm_tile(
    const short* __restrict__ A, const short* __restrict__ Bt,
    const float* __restrict__ bias, short* __restrict__ out, int ostride) {
  __shared__ short lds[16384];       // A tile [0,8192), B tile [8192,16384)
  const int t = threadIdx.x;
  const int l = t & 63, wv = t >> 6;
  const int m0 = blockIdx.x * 128;
  const int n0 = blockIdx.y * 128;
  const int r = l & 15, q = l >> 4;
  const int wm = wv & 1, wn = wv >> 1;

  f32x4 acc[4][4];
#pragma unroll
  for (int a = 0; a < 4; ++a)
#pragma unroll
    for (int c = 0; c < 4; ++c) acc[a][c] = (f32x4){0.f, 0.f, 0.f, 0.f};

  for (int kt = 0; kt < 4; ++kt) {
    const int k0 = kt * 64;
    if (kt) __syncthreads();
#pragma unroll
    for (int j = 0; j < 4; ++j) {
      int flat = (j * 4 + wv) * 64 + l;
      int row = flat >> 3;
      int cs = (flat & 7) ^ (row & 7);
      gload_lds16(A + (m0 + row) * 256 + k0 + cs * 8, lds + (j * 4 + wv) * 512);
      gload_lds16(Bt + (n0 + row) * 256 + k0 + cs * 8,
                  lds + 8192 + (j * 4 + wv) * 512);
    }
    __syncthreads();
    bf16x8 af[2][4], bfr[2][4];
#pragma unroll
    for (int kh = 0; kh < 2; ++kh) {
#pragma unroll
      for (int a = 0; a < 4; ++a) {
        int R = wm * 64 + a * 16 + r;
        int s = (kh * 4 + q) ^ (R & 7);
        af[kh][a] = *(const bf16x8*)(lds + R * 64 + s * 8);
      }
#pragma unroll
      for (int c = 0; c < 4; ++c) {
        int R = wn * 64 + c * 16 + r;
        int s = (kh * 4 + q) ^ (R & 7);
        bfr[kh][c] = *(const bf16x8*)(lds + 8192 + R * 64 + s * 8);
      }
    }
#pragma unroll
    for (int kh = 0; kh < 2; ++kh)
#pragma unroll
      for (int a = 0; a < 4; ++a)
#pragma unroll
        for (int c = 0; c < 4; ++c)
          acc[a][c] = __builtin_amdgcn_mfma_f32_16x16x32_bf16(
              af[kh][a], bfr[kh][c], acc[a][c], 0, 0, 0);
  }
#pragma unroll
  for (int c = 0; c < 4; ++c) {
    int n = n0 + wn * 64 + c * 16 + r;
    float bs = bias[n];
#pragma unroll
    for (int a = 0; a < 4; ++a)
#pragma unroll
      for (int i = 0; i < 4; ++i) {
        int m = m0 + wm * 64 + a * 16 + q * 4 + i;
        float v = acc[a][c][i] + bs;
        if (RELU) v = fmaxf(v, 0.f);
        out[m * ostride + n] = f2b(v);
      }
  }
}

// ---------- per-pixel GATv2 + residual + layernorm (chunk-local) ------------
// XLRc: [4*CPIX rows][512] = [xl | xr]
__global__ __launch_bounds__(256) void attn_ln(
    const short* __restrict__ XLRc,
    const float* __restrict__ att, const float* __restrict__ bias,
    const float* __restrict__ lng, const float* __restrict__ lnb,
    short* __restrict__ Xc, int pOff, short* rowsPad, short* fimgb,
    int writeFused) {
  int lane = threadIdx.x & 63;
  int lp = blockIdx.x * 4 + (threadIdx.x >> 6);
  int p = pOff + lp;

  float xl[4][4], xr[4][4], xres[4][4];
#pragma unroll
  for (int i = 0; i < 4; ++i)
#pragma unroll
    for (int h = 0; h < 4; ++h) {
      int rrow = (lp * 4 + i) * 512 + h * 64 + lane;
      xl[i][h] = b2f(XLRc[rrow]);
      xr[i][h] = b2f(XLRc[rrow + 256]);
      xres[i][h] = b2f(Xc[(lp * 4 + i) * 256 + h * 64 + lane]);
    }
  float attr[4], biasr[4], gr[4], br[4];
#pragma unroll
  for (int h = 0; h < 4; ++h) {
    attr[h] = att[h * 64 + lane];
    biasr[h] = bias[h * 64 + lane];
    gr[h] = lng[h * 64 + lane];
    br[h] = lnb[h * 64 + lane];
  }

  float outv[4][4];
#pragma unroll
  for (int i = 0; i < 4; ++i) {
#pragma unroll
    for (int h = 0; h < 4; ++h) {
      float s[4];
#pragma unroll
      for (int j = 0; j < 4; ++j) {
        float t = xr[i][h] + xl[j][h];
        t = fmaxf(t, 0.f) + 0.2f * fminf(t, 0.f);
        s[j] = wsum(t * attr[h]);
      }
      float mx = fmaxf(fmaxf(s[0], s[1]), fmaxf(s[2], s[3]));
      float e0 = expf(s[0] - mx), e1 = expf(s[1] - mx);
      float e2 = expf(s[2] - mx), e3 = expf(s[3] - mx);
      float inv = 1.f / (e0 + e1 + e2 + e3);
      outv[i][h] = (e0 * xl[0][h] + e1 * xl[1][h] + e2 * xl[2][h] + e3 * xl[3][h]) * inv;
    }
  }
#pragma unroll
  for (int i = 0; i < 4; ++i) {
    float y[4];
#pragma unroll
    for (int h = 0; h < 4; ++h) y[h] = outv[i][h] + biasr[h] + xres[i][h];
    float mu = wsum(y[0] + y[1] + y[2] + y[3]) * (1.f / 256.f);
    float d[4], vs = 0.f;
#pragma unroll
    for (int h = 0; h < 4; ++h) { d[h] = y[h] - mu; vs += d[h] * d[h]; }
    float var = wsum(vs) * (1.f / 256.f);
    float rs = rsqrtf(var + 1e-5f);
#pragma unroll
    for (int h = 0; h < 4; ++h) {
      short ob = f2b(d[h] * rs * gr[h] + br[h]);
      Xc[(lp * 4 + i) * 256 + h * 64 + lane] = ob;
      if (writeFused && i == 0) {
        int c = h * 64 + lane;
        int w = p & 127, hh = (p >> 7) & 127, b = p >> 14;
        rowsPad[((b * PADR + (hh + 1) * 130 + (w + 1)) * 256) + c] = ob;
        fimgb[((b * 256 + c) * 128 + hh) * 128 + w] = ob;
      }
    }
  }
}

// ---------- conv3x3: tiled 9-tap GEMM + BN + ReLU + residual ----------------
// A = cwt[tap] (M=256 cout), B = padded fused rows (N=32768 pixels).
// block: 128 cout x 128 pixels (one full image row), K = 9 taps x 256.
__global__ __launch_bounds__(256) void conv_tile(
    const short* __restrict__ cwt, const short* __restrict__ rowsPad,
    const short* __restrict__ fimgb, const float* __restrict__ bnp,
    const int* __restrict__ flag, void* __restrict__ outp) {
  __shared__ short lds[16384];
  const int bf = *flag;
  const int t = threadIdx.x;
  const int l = t & 63, wv = t >> 6;
  const int pb = blockIdx.x;          // 0..255: (batch, image row)
  const int bb = pb >> 7, h = pb & 127;
  const int m0 = blockIdx.y * 128;    // cout base
  const int r = l & 15, q = l >> 4;
  const int wm = wv & 1, wn = wv >> 1;

  f32x4 acc[4][4];
#pragma unroll
  for (int a = 0; a < 4; ++a)
#pragma unroll
    for (int c = 0; c < 4; ++c) acc[a][c] = (f32x4){0.f, 0.f, 0.f, 0.f};

  for (int tap = 0; tap < 9; ++tap) {
    const int ty = tap / 3, tx = tap - ty * 3;
    const int prow0 = bb * PADR + (h + ty) * 130 + tx;
    const short* Abase = cwt + tap * 65536;
    for (int kt = 0; kt < 4; ++kt) {
      const int k0 = kt * 64;
      if (tap | kt) __syncthreads();
#pragma unroll
      for (int j = 0; j < 4; ++j) {
        int flat = (j * 4 + wv) * 64 + l;
        int row = flat >> 3;
        int cs = (flat & 7) ^ (row & 7);
        gload_lds16(Abase + (m0 + row) * 256 + k0 + cs * 8,
                    lds + (j * 4 + wv) * 512);
        gload_lds16(rowsPad + (prow0 + row) * 256 + k0 + cs * 8,
                    lds + 8192 + (j * 4 + wv) * 512);
      }
      __syncthreads();
      bf16x8 af[2][4], bfr[2][4];
#pragma unroll
      for (int kh = 0; kh < 2; ++kh) {
#pragma unroll
        for (int a = 0; a < 4; ++a) {
          int R = wm * 64 + a * 16 + r;
          int s = (kh * 4 + q) ^ (R & 7);
          af[kh][a] = *(const bf16x8*)(lds + R * 64 + s * 8);
        }
#pragma unroll
        for (int c = 0; c < 4; ++c) {
          int R = wn * 64 + c * 16 + r;
          int s = (kh * 4 + q) ^ (R & 7);
          bfr[kh][c] = *(const bf16x8*)(lds + 8192 + R * 64 + s * 8);
        }
      }
#pragma unroll
      for (int kh = 0; kh < 2; ++kh)
#pragma unroll
        for (int a = 0; a < 4; ++a)
#pragma unroll
          for (int c = 0; c < 4; ++c)
            acc[a][c] = __builtin_amdgcn_mfma_f32_16x16x32_bf16(
                af[kh][a], bfr[kh][c], acc[a][c], 0, 0, 0);
    }
  }
#pragma unroll
  for (int c = 0; c < 4; ++c) {
    int w = wn * 64 + c * 16 + r;
#pragma unroll
    for (int a = 0; a < 4; ++a)
#pragma unroll
      for (int i = 0; i < 4; ++i) {
        int m = m0 + wm * 64 + a * 16 + q * 4 + i;   // cout
        float scale = rsqrtf(bnp[768 + m] + 1e-5f) * bnp[m];
        float v = (acc[a][c][i] - bnp[512 + m]) * scale + bnp[256 + m];
        v = fmaxf(v, 0.f);
        int idx = ((bb * 256 + m) * 128 + h) * 128 + w;
        float res = v + b2f(fimgb[idx]);
        if (bf) ((short*)outp)[idx] = f2b(res);
        else    ((float*)outp)[idx] = res;
      }
  }
}

extern "C" void kernel_launch(void* const* d_in, const int* in_sizes, int n_in,
                              void* d_out, int out_size, void* d_ws, size_t ws_size,
                              hipStream_t stream) {
  // ws layout (shorts). Total ~61.2 MB (round-3-proven size class).
  short* ws = (short*)d_ws;
  short* FROWSP = ws;                      // 2*130*130*256 = 8,652,800
  short* FIMG   = ws + 8652800;            // 8,388,608
  short* XLRc   = ws + 17041408;           // 4*CPIX*512   = 8,388,608
  short* Xc     = ws + 25430016;           // 4*CPIX*256   = 4,194,304
  short* WT     = ws + 29624320;           // 6 x 65536
  short* CWT    = ws + 30017536;           // 9 x 65536
  float* PB     = (float*)(ws + 30607360); // 18 x 256 fp32
  int*   FLAG   = (int*)(ws + 30616576);
  short* MEANc  = XLRc;                    // alias (dead before proj writes)
  short* H1c    = XLRc + 1048576;          // alias

  detect_dtype<<<1, 256, 0, stream>>>(d_in[3], FLAG);

  P18 pp;
  pp.p[0] = d_in[4];   pp.p[1] = d_in[6];   // fn_b1, fn_b2
  pp.p[2] = d_in[8];   pp.p[3] = d_in[10];  // l0_bl, l0_br (adjacent -> 512 bias)
  pp.p[4] = d_in[11];  pp.p[5] = d_in[12];  // l0_att, l0_bias
  pp.p[6] = d_in[13];  pp.p[7] = d_in[14];  // ln0_g, ln0_b
  pp.p[8] = d_in[16];  pp.p[9] = d_in[18];  // l1_bl, l1_br
  pp.p[10] = d_in[19]; pp.p[11] = d_in[20]; // l1_att, l1_bias
  pp.p[12] = d_in[21]; pp.p[13] = d_in[22]; // ln1_g, ln1_b
  pp.p[14] = d_in[24]; pp.p[15] = d_in[25]; // bn_g, bn_b
  pp.p[16] = d_in[26]; pp.p[17] = d_in[27]; // bn_m, bn_v
  prep_params<<<1, 256, 0, stream>>>(pp, FLAG, PB);

  prep_gemm_w<<<dim3(256, 6), 256, 0, stream>>>(d_in[3], d_in[5], d_in[7],
                                                d_in[9], d_in[15], d_in[17],
                                                FLAG, WT);
  prep_conv_w<<<2304, 256, 0, stream>>>(d_in[23], FLAG, CWT);
  zero_border<<<1032, 256, 0, stream>>>(FROWSP);

  for (int ci = 0; ci < NCH; ++ci) {
    gather_chunk<<<64, 256, 0, stream>>>(d_in[0], d_in[1], d_in[2], FLAG, Xc,
                                         MEANc, ci * 64);
    // fusion MLP: MEANc -> H1c -> Xc node 0
    gemm_tile<1><<<dim3(CPIX / 128, 2), 256, 0, stream>>>(
        MEANc, WT + 0 * 65536, PB + 0 * 256, H1c, 256);
    gemm_tile<0><<<dim3(CPIX / 128, 2), 256, 0, stream>>>(
        H1c, WT + 1 * 65536, PB + 1 * 256, Xc, 1024);
    for (int lyr = 0; lyr < 2; ++lyr) {
      // fused [Wl|Wr] projection: N=512
      gemm_tile<0><<<dim3(4 * CPIX / 128, 4), 256, 0, stream>>>(
          Xc, WT + (2 + 2 * lyr) * 65536, PB + (2 + 6 * lyr) * 256, XLRc, 512);
      attn_ln<<<CPIX / 4, 256, 0, stream>>>(
          XLRc, PB + (4 + 6 * lyr) * 256, PB + (5 + 6 * lyr) * 256,
          PB + (6 + 6 * lyr) * 256, PB + (7 + 6 * lyr) * 256, Xc, ci * CPIX,
          FROWSP, FIMG, lyr);
    }
  }

  conv_tile<<<dim3(256, 2), 256, 0, stream>>>(CWT, FROWSP, FIMG, PB + 14 * 256,
                                              FLAG, d_out);
}

// Round 5
// 986.567 us; speedup vs baseline: 2.4440x; 1.7324x over previous
//
#include <hip/hip_runtime.h>

// GNNRoIFusion on MI355X (gfx950).
// B=2, H=W=128, C=256, HEADS=4, D=64, M=3, P=32768 pixels.
// Round 5: adaptive chunking from ws_size (NCH in {1,2,4,8}); kernel bodies
// identical to round-4 verified versions. NCH=1 -> 13 large dispatches.

#define Pn 32768
#define PADR 16900  // 130*130 padded rows per batch

typedef __attribute__((ext_vector_type(8))) short bf16x8;
typedef __attribute__((ext_vector_type(4))) float f32x4;

__device__ __forceinline__ float b2f(short s) {
  unsigned u = ((unsigned)(unsigned short)s) << 16;
  float f;
  __builtin_memcpy(&f, &u, 4);
  return f;
}
__device__ __forceinline__ short f2b(float f) {
  unsigned u;
  __builtin_memcpy(&u, &f, 4);
  u += 0x7fffu + ((u >> 16) & 1u);   // RNE to bf16
  return (short)(u >> 16);
}
__device__ __forceinline__ float ldany(const void* p, int i, int bf) {
  return bf ? b2f(((const short*)p)[i]) : ((const float*)p)[i];
}
__device__ __forceinline__ float wsum(float v) {
#pragma unroll
  for (int m = 1; m < 64; m <<= 1) v += __shfl_xor(v, m, 64);
  return v;
}
// async global->LDS, 16B per lane; lds base wave-uniform, lane i -> base+16i
__device__ __forceinline__ void gload_lds16(const short* g, short* l) {
  __builtin_amdgcn_global_load_lds(
      (const __attribute__((address_space(1))) unsigned int*)g,
      (__attribute__((address_space(3))) unsigned int*)l, 16, 0, 0);
}

// ---------- dtype probe ------------------------------------------------------
__global__ __launch_bounds__(256) void detect_dtype(const void* probe, int* flag) {
  const short* s = (const short*)probe;
  int cnt = 0;
#pragma unroll
  for (int i = 0; i < 8; ++i) {
    short v = s[(threadIdx.x * 8 + i) * 2];
    int e = ((unsigned short)v >> 7) & 0xFF;
    cnt += (e >= 100 && e <= 127) ? 1 : 0;
  }
  __shared__ int tot;
  if (threadIdx.x == 0) tot = 0;
  __syncthreads();
  atomicAdd(&tot, cnt);
  __syncthreads();
  if (threadIdx.x == 0) flag[0] = (tot > 1024) ? 1 : 0;  // 1 = bf16 inputs
}

// ---------- small params -> fp32 block (18 vectors of 256) ------------------
struct P18 { const void* p[18]; };
__global__ __launch_bounds__(256) void prep_params(P18 s, const int* flag, float* pb) {
  int bf = *flag;
  int t = threadIdx.x;
#pragma unroll
  for (int v = 0; v < 18; ++v) pb[v * 256 + t] = ldany(s.p[v], t, bf);
}

// ---------- weight prep: Wt[n][k] = W[k][n] (bf16) --------------------------
__global__ __launch_bounds__(256) void prep_gemm_w(
    const void* w0, const void* w1, const void* w2, const void* w3,
    const void* w4, const void* w5, const int* flag, short* wt) {
  int bf = *flag;
  const void* src;
  switch (blockIdx.y) {
    case 0: src = w0; break;
    case 1: src = w1; break;
    case 2: src = w2; break;
    case 3: src = w3; break;
    case 4: src = w4; break;
    default: src = w5; break;
  }
  int idx = blockIdx.x * 256 + threadIdx.x;     // n*256 + k
  int n = idx >> 8, k = idx & 255;
  wt[blockIdx.y * 65536 + idx] = f2b(ldany(src, k * 256 + n, bf));
}

// conv_w [cout][cin][3][3] -> cwt[tap][cout][cin]
__global__ __launch_bounds__(256) void prep_conv_w(const void* cw, const int* flag,
                                                   short* cwt) {
  int bf = *flag;
  int idx = blockIdx.x * 256 + threadIdx.x;
  int tap = idx >> 16;
  int n = (idx >> 8) & 255;
  int k = idx & 255;
  cwt[idx] = f2b(ldany(cw, (n * 256 + k) * 9 + tap, bf));
}

// ---------- zero the halo of FROWSpad [2][130][130][256] --------------------
__global__ __launch_bounds__(256) void zero_border(short* rowsPad) {
  int id = blockIdx.x;              // 0..1031
  int b = id >= 516;
  int r = id - b * 516;
  int hp, wp;
  if (r < 130)      { hp = 0;       wp = r; }
  else if (r < 260) { hp = 129;     wp = r - 130; }
  else if (r < 388) { hp = r - 259; wp = 0; }
  else              { hp = r - 387; wp = 129; }
  rowsPad[(b * PADR + hp * 130 + wp) * 256 + threadIdx.x] = 0;
}

// ---------- gather chunk: modal [B,C,H,W] -> Xc nodes 1..3 + MEANc ----------
__global__ __launch_bounds__(256) void gather_chunk(
    const void* m0, const void* m1, const void* m2, const int* flag,
    short* Xc, short* meanc, int sb0) {
  int bf = *flag;
  int sb = sb0 + blockIdx.x;        // 64-pixel segment
  int wt = sb & 1, h = (sb >> 1) & 127, b = sb >> 8;
  int w0 = wt * 64;
  int tid = threadIdx.x;
  __shared__ float tile[64][65];
  const void* srcs[3] = {m0, m1, m2};
  int lp0 = blockIdx.x * 64;

  for (int cb = 0; cb < 256; cb += 64) {
    float macc[16];
#pragma unroll
    for (int i = 0; i < 16; ++i) macc[i] = 0.f;
#pragma unroll
    for (int m = 0; m < 3; ++m) {
      __syncthreads();
      for (int cc = 0; cc < 16; ++cc) {
        int c_l = (tid >> 6) + cc * 4;
        int gidx = ((b * 256 + cb + c_l) * 128 + h) * 128 + w0 + (tid & 63);
        tile[c_l][tid & 63] = ldany(srcs[m], gidx, bf);
      }
      __syncthreads();
      int c_l = tid & 63;
      for (int ww = 0; ww < 16; ++ww) {
        int w_l = (tid >> 6) + ww * 4;
        float v = tile[c_l][w_l];
        macc[ww] += v;
        Xc[((lp0 + w_l) * 4 + 1 + m) * 256 + cb + c_l] = f2b(v);
      }
    }
    int c_l = tid & 63;
    for (int ww = 0; ww < 16; ++ww) {
      int w_l = (tid >> 6) + ww * 4;
      meanc[(lp0 + w_l) * 256 + cb + c_l] = f2b(macc[ww] * (1.f / 3.f));
    }
  }
}

// ---------- tiled GEMM: out[m*ostride+n] = A[M,256] @ Bt[n][256]^T + bias ---
// block = 128 rows x 128 cols, 4 waves of 64x64; BK=64, K=256 (4 iters).
// LDS XOR-swizzle: physical 16B-chunk slot = logical_chunk ^ (row & 7).
template <int RELU>
__global__ __launch_bounds__(256) void gemm_tile(
    const short* __restrict__ A, const short* __restrict__ Bt,
    const float* __restrict__ bias, short* __restrict__ out, int ostride) {
  __shared__ short lds[16384];       // A tile [0,8192), B tile [8192,16384)
  const int t = threadIdx.x;
  const int l = t & 63, wv = t >> 6;
  const int m0 = blockIdx.x * 128;
  const int n0 = blockIdx.y * 128;
  const int r = l & 15, q = l >> 4;
  const int wm = wv & 1, wn = wv >> 1;

  f32x4 acc[4][4];
#pragma unroll
  for (int a = 0; a < 4; ++a)
#pragma unroll
    for (int c = 0; c < 4; ++c) acc[a][c] = (f32x4){0.f, 0.f, 0.f, 0.f};

  for (int kt = 0; kt < 4; ++kt) {
    const int k0 = kt * 64;
    if (kt) __syncthreads();
#pragma unroll
    for (int j = 0; j < 4; ++j) {
      int flat = (j * 4 + wv) * 64 + l;
      int row = flat >> 3;
      int cs = (flat & 7) ^ (row & 7);
      gload_lds16(A + (m0 + row) * 256 + k0 + cs * 8, lds + (j * 4 + wv) * 512);
      gload_lds16(Bt + (n0 + row) * 256 + k0 + cs * 8,
                  lds + 8192 + (j * 4 + wv) * 512);
    }
    __syncthreads();
    bf16x8 af[2][4], bfr[2][4];
#pragma unroll
    for (int kh = 0; kh < 2; ++kh) {
#pragma unroll
      for (int a = 0; a < 4; ++a) {
        int R = wm * 64 + a * 16 + r;
        int s = (kh * 4 + q) ^ (R & 7);
        af[kh][a] = *(const bf16x8*)(lds + R * 64 + s * 8);
      }
#pragma unroll
      for (int c = 0; c < 4; ++c) {
        int R = wn * 64 + c * 16 + r;
        int s = (kh * 4 + q) ^ (R & 7);
        bfr[kh][c] = *(const bf16x8*)(lds + 8192 + R * 64 + s * 8);
      }
    }
#pragma unroll
    for (int kh = 0; kh < 2; ++kh)
#pragma unroll
      for (int a = 0; a < 4; ++a)
#pragma unroll
        for (int c = 0; c < 4; ++c)
          acc[a][c] = __builtin_amdgcn_mfma_f32_16x16x32_bf16(
              af[kh][a], bfr[kh][c], acc[a][c], 0, 0, 0);
  }
#pragma unroll
  for (int c = 0; c < 4; ++c) {
    int n = n0 + wn * 64 + c * 16 + r;
    float bs = bias[n];
#pragma unroll
    for (int a = 0; a < 4; ++a)
#pragma unroll
      for (int i = 0; i < 4; ++i) {
        int m = m0 + wm * 64 + a * 16 + q * 4 + i;
        float v = acc[a][c][i] + bs;
        if (RELU) v = fmaxf(v, 0.f);
        out[m * ostride + n] = f2b(v);
      }
  }
}

// ---------- per-pixel GATv2 + residual + layernorm (chunk-local) ------------
// XLRc: [4*CPIX rows][512] = [xl | xr]
__global__ __launch_bounds__(256) void attn_ln(
    const short* __restrict__ XLRc,
    const float* __restrict__ att, const float* __restrict__ bias,
    const float* __restrict__ lng, const float* __restrict__ lnb,
    short* __restrict__ Xc, int pOff, short* rowsPad, short* fimgb,
    int writeFused) {
  int lane = threadIdx.x & 63;
  int lp = blockIdx.x * 4 + (threadIdx.x >> 6);
  int p = pOff + lp;

  float xl[4][4], xr[4][4], xres[4][4];
#pragma unroll
  for (int i = 0; i < 4; ++i)
#pragma unroll
    for (int h = 0; h < 4; ++h) {
      int rrow = (lp * 4 + i) * 512 + h * 64 + lane;
      xl[i][h] = b2f(XLRc[rrow]);
      xr[i][h] = b2f(XLRc[rrow + 256]);
      xres[i][h] = b2f(Xc[(lp * 4 + i) * 256 + h * 64 + lane]);
    }
  float attr[4], biasr[4], gr[4], br[4];
#pragma unroll
  for (int h = 0; h < 4; ++h) {
    attr[h] = att[h * 64 + lane];
    biasr[h] = bias[h * 64 + lane];
    gr[h] = lng[h * 64 + lane];
    br[h] = lnb[h * 64 + lane];
  }

  float outv[4][4];
#pragma unroll
  for (int i = 0; i < 4; ++i) {
#pragma unroll
    for (int h = 0; h < 4; ++h) {
      float s[4];
#pragma unroll
      for (int j = 0; j < 4; ++j) {
        float t = xr[i][h] + xl[j][h];
        t = fmaxf(t, 0.f) + 0.2f * fminf(t, 0.f);
        s[j] = wsum(t * attr[h]);
      }
      float mx = fmaxf(fmaxf(s[0], s[1]), fmaxf(s[2], s[3]));
      float e0 = expf(s[0] - mx), e1 = expf(s[1] - mx);
      float e2 = expf(s[2] - mx), e3 = expf(s[3] - mx);
      float inv = 1.f / (e0 + e1 + e2 + e3);
      outv[i][h] = (e0 * xl[0][h] + e1 * xl[1][h] + e2 * xl[2][h] + e3 * xl[3][h]) * inv;
    }
  }
#pragma unroll
  for (int i = 0; i < 4; ++i) {
    float y[4];
#pragma unroll
    for (int h = 0; h < 4; ++h) y[h] = outv[i][h] + biasr[h] + xres[i][h];
    float mu = wsum(y[0] + y[1] + y[2] + y[3]) * (1.f / 256.f);
    float d[4], vs = 0.f;
#pragma unroll
    for (int h = 0; h < 4; ++h) { d[h] = y[h] - mu; vs += d[h] * d[h]; }
    float var = wsum(vs) * (1.f / 256.f);
    float rs = rsqrtf(var + 1e-5f);
#pragma unroll
    for (int h = 0; h < 4; ++h) {
      short ob = f2b(d[h] * rs * gr[h] + br[h]);
      Xc[(lp * 4 + i) * 256 + h * 64 + lane] = ob;
      if (writeFused && i == 0) {
        int c = h * 64 + lane;
        int w = p & 127, hh = (p >> 7) & 127, b = p >> 14;
        rowsPad[((b * PADR + (hh + 1) * 130 + (w + 1)) * 256) + c] = ob;
        fimgb[((b * 256 + c) * 128 + hh) * 128 + w] = ob;
      }
    }
  }
}

// ---------- conv3x3: tiled 9-tap GEMM + BN + ReLU + residual ----------------
__global__ __launch_bounds__(256) void conv_tile(
    const short* __restrict__ cwt, const short* __restrict__ rowsPad,
    const short* __restrict__ fimgb, const float* __restrict__ bnp,
    const int* __restrict__ flag, void* __restrict__ outp) {
  __shared__ short lds[16384];
  const int bf = *flag;
  const int t = threadIdx.x;
  const int l = t & 63, wv = t >> 6;
  const int pb = blockIdx.x;          // 0..255: (batch, image row)
  const int bb = pb >> 7, h = pb & 127;
  const int m0 = blockIdx.y * 128;    // cout base
  const int r = l & 15, q = l >> 4;
  const int wm = wv & 1, wn = wv >> 1;

  f32x4 acc[4][4];
#pragma unroll
  for (int a = 0; a < 4; ++a)
#pragma unroll
    for (int c = 0; c < 4; ++c) acc[a][c] = (f32x4){0.f, 0.f, 0.f, 0.f};

  for (int tap = 0; tap < 9; ++tap) {
    const int ty = tap / 3, tx = tap - ty * 3;
    const int prow0 = bb * PADR + (h + ty) * 130 + tx;
    const short* Abase = cwt + tap * 65536;
    for (int kt = 0; kt < 4; ++kt) {
      const int k0 = kt * 64;
      if (tap | kt) __syncthreads();
#pragma unroll
      for (int j = 0; j < 4; ++j) {
        int flat = (j * 4 + wv) * 64 + l;
        int row = flat >> 3;
        int cs = (flat & 7) ^ (row & 7);
        gload_lds16(Abase + (m0 + row) * 256 + k0 + cs * 8,
                    lds + (j * 4 + wv) * 512);
        gload_lds16(rowsPad + (prow0 + row) * 256 + k0 + cs * 8,
                    lds + 8192 + (j * 4 + wv) * 512);
      }
      __syncthreads();
      bf16x8 af[2][4], bfr[2][4];
#pragma unroll
      for (int kh = 0; kh < 2; ++kh) {
#pragma unroll
        for (int a = 0; a < 4; ++a) {
          int R = wm * 64 + a * 16 + r;
          int s = (kh * 4 + q) ^ (R & 7);
          af[kh][a] = *(const bf16x8*)(lds + R * 64 + s * 8);
        }
#pragma unroll
        for (int c = 0; c < 4; ++c) {
          int R = wn * 64 + c * 16 + r;
          int s = (kh * 4 + q) ^ (R & 7);
          bfr[kh][c] = *(const bf16x8*)(lds + 8192 + R * 64 + s * 8);
        }
      }
#pragma unroll
      for (int kh = 0; kh < 2; ++kh)
#pragma unroll
        for (int a = 0; a < 4; ++a)
#pragma unroll
          for (int c = 0; c < 4; ++c)
            acc[a][c] = __builtin_amdgcn_mfma_f32_16x16x32_bf16(
                af[kh][a], bfr[kh][c], acc[a][c], 0, 0, 0);
    }
  }
#pragma unroll
  for (int c = 0; c < 4; ++c) {
    int w = wn * 64 + c * 16 + r;
#pragma unroll
    for (int a = 0; a < 4; ++a)
#pragma unroll
      for (int i = 0; i < 4; ++i) {
        int m = m0 + wm * 64 + a * 16 + q * 4 + i;   // cout
        float scale = rsqrtf(bnp[768 + m] + 1e-5f) * bnp[m];
        float v = (acc[a][c][i] - bnp[512 + m]) * scale + bnp[256 + m];
        v = fmaxf(v, 0.f);
        int idx = ((bb * 256 + m) * 128 + h) * 128 + w;
        float res = v + b2f(fimgb[idx]);
        if (bf) ((short*)outp)[idx] = f2b(res);
        else    ((float*)outp)[idx] = res;
      }
  }
}

extern "C" void kernel_launch(void* const* d_in, const int* in_sizes, int n_in,
                              void* d_out, int out_size, void* d_ws, size_t ws_size,
                              hipStream_t stream) {
  // Adaptive chunking: pick smallest NCH whose footprint fits ws_size.
  // base (shorts): FROWSP 8,652,800 + FIMG 8,388,608 + WT 393,216 +
  //                CWT 589,824 + PB 9,216 + FLAG 16 = 18,033,680
  // extra = (32768/NCH)*3072 shorts (XLR + Xc).
  const long long baseS = 18033680LL;
  int NCH = 8;
  for (int cand = 1; cand <= 8; cand <<= 1) {
    long long tot = (baseS + (32768LL / cand) * 3072LL) * 2LL;
    if (tot <= (long long)ws_size) { NCH = cand; break; }
  }
  const int CPIX = 32768 / NCH;

  short* ws = (short*)d_ws;
  short* FROWSP = ws;                        // 8,652,800
  short* FIMG   = ws + 8652800;              // 8,388,608
  short* WT     = ws + 17041408;             // 393,216
  short* CWT    = ws + 17434624;             // 589,824
  float* PB     = (float*)(ws + 18024448);   // 18x256 fp32 (9,216 shorts)
  int*   FLAG   = (int*)(ws + 18033664);     // 16 shorts
  short* XLRc   = ws + 18033680;             // CPIX*2048
  short* Xc     = XLRc + (long long)CPIX * 2048;  // CPIX*1024
  short* MEANc  = XLRc;                      // alias (dead before proj writes)
  short* H1c    = XLRc + (long long)CPIX * 256;   // alias

  detect_dtype<<<1, 256, 0, stream>>>(d_in[3], FLAG);

  P18 pp;
  pp.p[0] = d_in[4];   pp.p[1] = d_in[6];   // fn_b1, fn_b2
  pp.p[2] = d_in[8];   pp.p[3] = d_in[10];  // l0_bl, l0_br (adjacent -> 512 bias)
  pp.p[4] = d_in[11];  pp.p[5] = d_in[12];  // l0_att, l0_bias
  pp.p[6] = d_in[13];  pp.p[7] = d_in[14];  // ln0_g, ln0_b
  pp.p[8] = d_in[16];  pp.p[9] = d_in[18];  // l1_bl, l1_br
  pp.p[10] = d_in[19]; pp.p[11] = d_in[20]; // l1_att, l1_bias
  pp.p[12] = d_in[21]; pp.p[13] = d_in[22]; // ln1_g, ln1_b
  pp.p[14] = d_in[24]; pp.p[15] = d_in[25]; // bn_g, bn_b
  pp.p[16] = d_in[26]; pp.p[17] = d_in[27]; // bn_m, bn_v
  prep_params<<<1, 256, 0, stream>>>(pp, FLAG, PB);

  prep_gemm_w<<<dim3(256, 6), 256, 0, stream>>>(d_in[3], d_in[5], d_in[7],
                                                d_in[9], d_in[15], d_in[17],
                                                FLAG, WT);
  prep_conv_w<<<2304, 256, 0, stream>>>(d_in[23], FLAG, CWT);
  zero_border<<<1032, 256, 0, stream>>>(FROWSP);

  for (int ci = 0; ci < NCH; ++ci) {
    gather_chunk<<<CPIX / 64, 256, 0, stream>>>(d_in[0], d_in[1], d_in[2],
                                                FLAG, Xc, MEANc,
                                                ci * (CPIX / 64));
    // fusion MLP: MEANc -> H1c -> Xc node 0
    gemm_tile<1><<<dim3(CPIX / 128, 2), 256, 0, stream>>>(
        MEANc, WT + 0 * 65536, PB + 0 * 256, H1c, 256);
    gemm_tile<0><<<dim3(CPIX / 128, 2), 256, 0, stream>>>(
        H1c, WT + 1 * 65536, PB + 1 * 256, Xc, 1024);
    for (int lyr = 0; lyr < 2; ++lyr) {
      // fused [Wl|Wr] projection: N=512
      gemm_tile<0><<<dim3(4 * CPIX / 128, 4), 256, 0, stream>>>(
          Xc, WT + (2 + 2 * lyr) * 65536, PB + (2 + 6 * lyr) * 256, XLRc, 512);
      attn_ln<<<CPIX / 4, 256, 0, stream>>>(
          XLRc, PB + (4 + 6 * lyr) * 256, PB + (5 + 6 * lyr) * 256,
          PB + (6 + 6 * lyr) * 256, PB + (7 + 6 * lyr) * 256, Xc, ci * CPIX,
          FROWSP, FIMG, lyr);
    }
  }

  conv_tile<<<dim3(256, 2), 256, 0, stream>>>(CWT, FROWSP, FIMG, PB + 14 * 256,
                                              FLAG, d_out);
}

// Round 6
// 796.220 us; speedup vs baseline: 3.0283x; 1.2391x over previous
//
#include <hip/hip_runtime.h>

// GNNRoIFusion on MI355X (gfx950).
// B=2, H=W=128, C=256, HEADS=4, D=64, M=3, P=32768 pixels.
// Round 6: attn_ln restructured to 4 pixels/wave (16-lane groups, d-chunk-4
// per lane): 384->64 shuffles/pixel, softmax/LN amortized 4x. Others as r5.

#define Pn 32768
#define PADR 16900  // 130*130 padded rows per batch

typedef __attribute__((ext_vector_type(8))) short bf16x8;
typedef __attribute__((ext_vector_type(4))) float f32x4;
typedef __attribute__((ext_vector_type(4))) unsigned short u16x4;

__device__ __forceinline__ float b2f(short s) {
  unsigned u = ((unsigned)(unsigned short)s) << 16;
  float f;
  __builtin_memcpy(&f, &u, 4);
  return f;
}
__device__ __forceinline__ short f2b(float f) {
  unsigned u;
  __builtin_memcpy(&u, &f, 4);
  u += 0x7fffu + ((u >> 16) & 1u);   // RNE to bf16
  return (short)(u >> 16);
}
__device__ __forceinline__ float ldany(const void* p, int i, int bf) {
  return bf ? b2f(((const short*)p)[i]) : ((const float*)p)[i];
}
// async global->LDS, 16B per lane; lds base wave-uniform, lane i -> base+16i
__device__ __forceinline__ void gload_lds16(const short* g, short* l) {
  __builtin_amdgcn_global_load_lds(
      (const __attribute__((address_space(1))) unsigned int*)g,
      (__attribute__((address_space(3))) unsigned int*)l, 16, 0, 0);
}

// ---------- dtype probe ------------------------------------------------------
__global__ __launch_bounds__(256) void detect_dtype(const void* probe, int* flag) {
  const short* s = (const short*)probe;
  int cnt = 0;
#pragma unroll
  for (int i = 0; i < 8; ++i) {
    short v = s[(threadIdx.x * 8 + i) * 2];
    int e = ((unsigned short)v >> 7) & 0xFF;
    cnt += (e >= 100 && e <= 127) ? 1 : 0;
  }
  __shared__ int tot;
  if (threadIdx.x == 0) tot = 0;
  __syncthreads();
  atomicAdd(&tot, cnt);
  __syncthreads();
  if (threadIdx.x == 0) flag[0] = (tot > 1024) ? 1 : 0;  // 1 = bf16 inputs
}

// ---------- small params -> fp32 block (18 vectors of 256) ------------------
struct P18 { const void* p[18]; };
__global__ __launch_bounds__(256) void prep_params(P18 s, const int* flag, float* pb) {
  int bf = *flag;
  int t = threadIdx.x;
#pragma unroll
  for (int v = 0; v < 18; ++v) pb[v * 256 + t] = ldany(s.p[v], t, bf);
}

// ---------- weight prep: Wt[n][k] = W[k][n] (bf16) --------------------------
__global__ __launch_bounds__(256) void prep_gemm_w(
    const void* w0, const void* w1, const void* w2, const void* w3,
    const void* w4, const void* w5, const int* flag, short* wt) {
  int bf = *flag;
  const void* src;
  switch (blockIdx.y) {
    case 0: src = w0; break;
    case 1: src = w1; break;
    case 2: src = w2; break;
    case 3: src = w3; break;
    case 4: src = w4; break;
    default: src = w5; break;
  }
  int idx = blockIdx.x * 256 + threadIdx.x;     // n*256 + k
  int n = idx >> 8, k = idx & 255;
  wt[blockIdx.y * 65536 + idx] = f2b(ldany(src, k * 256 + n, bf));
}

// conv_w [cout][cin][3][3] -> cwt[tap][cout][cin]
__global__ __launch_bounds__(256) void prep_conv_w(const void* cw, const int* flag,
                                                   short* cwt) {
  int bf = *flag;
  int idx = blockIdx.x * 256 + threadIdx.x;
  int tap = idx >> 16;
  int n = (idx >> 8) & 255;
  int k = idx & 255;
  cwt[idx] = f2b(ldany(cw, (n * 256 + k) * 9 + tap, bf));
}

// ---------- zero the halo of FROWSpad [2][130][130][256] --------------------
__global__ __launch_bounds__(256) void zero_border(short* rowsPad) {
  int id = blockIdx.x;              // 0..1031
  int b = id >= 516;
  int r = id - b * 516;
  int hp, wp;
  if (r < 130)      { hp = 0;       wp = r; }
  else if (r < 260) { hp = 129;     wp = r - 130; }
  else if (r < 388) { hp = r - 259; wp = 0; }
  else              { hp = r - 387; wp = 129; }
  rowsPad[(b * PADR + hp * 130 + wp) * 256 + threadIdx.x] = 0;
}

// ---------- gather chunk: modal [B,C,H,W] -> Xc nodes 1..3 + MEANc ----------
__global__ __launch_bounds__(256) void gather_chunk(
    const void* m0, const void* m1, const void* m2, const int* flag,
    short* Xc, short* meanc, int sb0) {
  int bf = *flag;
  int sb = sb0 + blockIdx.x;        // 64-pixel segment
  int wt = sb & 1, h = (sb >> 1) & 127, b = sb >> 8;
  int w0 = wt * 64;
  int tid = threadIdx.x;
  __shared__ float tile[64][65];
  const void* srcs[3] = {m0, m1, m2};
  int lp0 = blockIdx.x * 64;

  for (int cb = 0; cb < 256; cb += 64) {
    float macc[16];
#pragma unroll
    for (int i = 0; i < 16; ++i) macc[i] = 0.f;
#pragma unroll
    for (int m = 0; m < 3; ++m) {
      __syncthreads();
      for (int cc = 0; cc < 16; ++cc) {
        int c_l = (tid >> 6) + cc * 4;
        int gidx = ((b * 256 + cb + c_l) * 128 + h) * 128 + w0 + (tid & 63);
        tile[c_l][tid & 63] = ldany(srcs[m], gidx, bf);
      }
      __syncthreads();
      int c_l = tid & 63;
      for (int ww = 0; ww < 16; ++ww) {
        int w_l = (tid >> 6) + ww * 4;
        float v = tile[c_l][w_l];
        macc[ww] += v;
        Xc[((lp0 + w_l) * 4 + 1 + m) * 256 + cb + c_l] = f2b(v);
      }
    }
    int c_l = tid & 63;
    for (int ww = 0; ww < 16; ++ww) {
      int w_l = (tid >> 6) + ww * 4;
      meanc[(lp0 + w_l) * 256 + cb + c_l] = f2b(macc[ww] * (1.f / 3.f));
    }
  }
}

// ---------- tiled GEMM: out[m*ostride+n] = A[M,256] @ Bt[n][256]^T + bias ---
template <int RELU>
__global__ __launch_bounds__(256) void gemm_tile(
    const short* __restrict__ A, const short* __restrict__ Bt,
    const float* __restrict__ bias, short* __restrict__ out, int ostride) {
  __shared__ short lds[16384];       // A tile [0,8192), B tile [8192,16384)
  const int t = threadIdx.x;
  const int l = t & 63, wv = t >> 6;
  const int m0 = blockIdx.x * 128;
  const int n0 = blockIdx.y * 128;
  const int r = l & 15, q = l >> 4;
  const int wm = wv & 1, wn = wv >> 1;

  f32x4 acc[4][4];
#pragma unroll
  for (int a = 0; a < 4; ++a)
#pragma unroll
    for (int c = 0; c < 4; ++c) acc[a][c] = (f32x4){0.f, 0.f, 0.f, 0.f};

  for (int kt = 0; kt < 4; ++kt) {
    const int k0 = kt * 64;
    if (kt) __syncthreads();
#pragma unroll
    for (int j = 0; j < 4; ++j) {
      int flat = (j * 4 + wv) * 64 + l;
      int row = flat >> 3;
      int cs = (flat & 7) ^ (row & 7);
      gload_lds16(A + (m0 + row) * 256 + k0 + cs * 8, lds + (j * 4 + wv) * 512);
      gload_lds16(Bt + (n0 + row) * 256 + k0 + cs * 8,
                  lds + 8192 + (j * 4 + wv) * 512);
    }
    __syncthreads();
    bf16x8 af[2][4], bfr[2][4];
#pragma unroll
    for (int kh = 0; kh < 2; ++kh) {
#pragma unroll
      for (int a = 0; a < 4; ++a) {
        int R = wm * 64 + a * 16 + r;
        int s = (kh * 4 + q) ^ (R & 7);
        af[kh][a] = *(const bf16x8*)(lds + R * 64 + s * 8);
      }
#pragma unroll
      for (int c = 0; c < 4; ++c) {
        int R = wn * 64 + c * 16 + r;
        int s = (kh * 4 + q) ^ (R & 7);
        bfr[kh][c] = *(const bf16x8*)(lds + 8192 + R * 64 + s * 8);
      }
    }
#pragma unroll
    for (int kh = 0; kh < 2; ++kh)
#pragma unroll
      for (int a = 0; a < 4; ++a)
#pragma unroll
        for (int c = 0; c < 4; ++c)
          acc[a][c] = __builtin_amdgcn_mfma_f32_16x16x32_bf16(
              af[kh][a], bfr[kh][c], acc[a][c], 0, 0, 0);
  }
#pragma unroll
  for (int c = 0; c < 4; ++c) {
    int n = n0 + wn * 64 + c * 16 + r;
    float bs = bias[n];
#pragma unroll
    for (int a = 0; a < 4; ++a)
#pragma unroll
      for (int i = 0; i < 4; ++i) {
        int m = m0 + wm * 64 + a * 16 + q * 4 + i;
        float v = acc[a][c][i] + bs;
        if (RELU) v = fmaxf(v, 0.f);
        out[m * ostride + n] = f2b(v);
      }
  }
}

// ---------- per-pixel GATv2 + residual + layernorm --------------------------
// 4 pixels per wave: lane = p*16 + e; lane covers d = e*4..e*4+3 per head.
// 16-lane butterflies for score/LN reductions; softmax scalar per lane.
__global__ __launch_bounds__(256) void attn_ln(
    const short* __restrict__ XLRc,
    const float* __restrict__ att, const float* __restrict__ bias,
    const float* __restrict__ lng, const float* __restrict__ lnb,
    short* __restrict__ Xc, int pOff, short* rowsPad, short* fimgb,
    int writeFused) {
  const int lane = threadIdx.x & 63;
  const int wv = threadIdx.x >> 6;
  const int e = lane & 15;                       // d-quarter
  const int lp = blockIdx.x * 16 + wv * 4 + (lane >> 4);
  const int pg = pOff + lp;

  float out[4][4][4];    // [i][h][k]
#pragma unroll
  for (int h = 0; h < 4; ++h) {
    float av[4];
#pragma unroll
    for (int k = 0; k < 4; ++k) av[k] = att[h * 64 + e * 4 + k];
    float xlf[4][4], xrf[4][4];
#pragma unroll
    for (int j = 0; j < 4; ++j) {
      const short* rb = XLRc + (lp * 4 + j) * 512 + h * 64 + e * 4;
      u16x4 xlv = *(const u16x4*)rb;
      u16x4 xrv = *(const u16x4*)(rb + 256);
#pragma unroll
      for (int k = 0; k < 4; ++k) {
        xlf[j][k] = b2f((short)xlv[k]);
        xrf[j][k] = b2f((short)xrv[k]);
      }
    }
#pragma unroll
    for (int i = 0; i < 4; ++i) {
      float s[4];
#pragma unroll
      for (int j = 0; j < 4; ++j) {
        float a = 0.f;
#pragma unroll
        for (int k = 0; k < 4; ++k) {
          float t = xrf[i][k] + xlf[j][k];
          t = fmaxf(t, 0.f) + 0.2f * fminf(t, 0.f);   // leaky_relu 0.2
          a += t * av[k];
        }
        a += __shfl_xor(a, 1, 64);
        a += __shfl_xor(a, 2, 64);
        a += __shfl_xor(a, 4, 64);
        a += __shfl_xor(a, 8, 64);
        s[j] = a;
      }
      float mx = fmaxf(fmaxf(s[0], s[1]), fmaxf(s[2], s[3]));
      float e0 = expf(s[0] - mx), e1 = expf(s[1] - mx);
      float e2 = expf(s[2] - mx), e3 = expf(s[3] - mx);
      float inv = 1.f / (e0 + e1 + e2 + e3);
#pragma unroll
      for (int k = 0; k < 4; ++k)
        out[i][h][k] =
            (e0 * xlf[0][k] + e1 * xlf[1][k] + e2 * xlf[2][k] + e3 * xlf[3][k]) * inv;
    }
  }

  float biasf[4][4];
#pragma unroll
  for (int h = 0; h < 4; ++h)
#pragma unroll
    for (int k = 0; k < 4; ++k) biasf[h][k] = bias[h * 64 + e * 4 + k];

#pragma unroll
  for (int i = 0; i < 4; ++i) {
    float y[4][4], sm = 0.f;
#pragma unroll
    for (int h = 0; h < 4; ++h) {
      u16x4 rv = *(const u16x4*)(Xc + (lp * 4 + i) * 256 + h * 64 + e * 4);
#pragma unroll
      for (int k = 0; k < 4; ++k) {
        y[h][k] = out[i][h][k] + biasf[h][k] + b2f((short)rv[k]);
        sm += y[h][k];
      }
    }
    sm += __shfl_xor(sm, 1, 64);
    sm += __shfl_xor(sm, 2, 64);
    sm += __shfl_xor(sm, 4, 64);
    sm += __shfl_xor(sm, 8, 64);
    float mu = sm * (1.f / 256.f);
    float vs = 0.f;
#pragma unroll
    for (int h = 0; h < 4; ++h)
#pragma unroll
      for (int k = 0; k < 4; ++k) {
        float d = y[h][k] - mu;
        vs += d * d;
      }
    vs += __shfl_xor(vs, 1, 64);
    vs += __shfl_xor(vs, 2, 64);
    vs += __shfl_xor(vs, 4, 64);
    vs += __shfl_xor(vs, 8, 64);
    float rs = rsqrtf(vs * (1.f / 256.f) + 1e-5f);
#pragma unroll
    for (int h = 0; h < 4; ++h) {
      float g0 = lng[h * 64 + e * 4 + 0], g1 = lng[h * 64 + e * 4 + 1];
      float g2 = lng[h * 64 + e * 4 + 2], g3 = lng[h * 64 + e * 4 + 3];
      float b0 = lnb[h * 64 + e * 4 + 0], b1 = lnb[h * 64 + e * 4 + 1];
      float b2 = lnb[h * 64 + e * 4 + 2], b3 = lnb[h * 64 + e * 4 + 3];
      u16x4 ov;
      ov[0] = (unsigned short)f2b((y[h][0] - mu) * rs * g0 + b0);
      ov[1] = (unsigned short)f2b((y[h][1] - mu) * rs * g1 + b1);
      ov[2] = (unsigned short)f2b((y[h][2] - mu) * rs * g2 + b2);
      ov[3] = (unsigned short)f2b((y[h][3] - mu) * rs * g3 + b3);
      *(u16x4*)(Xc + (lp * 4 + i) * 256 + h * 64 + e * 4) = ov;
      if (writeFused && i == 0) {
        int w = pg & 127, hh = (pg >> 7) & 127, b = pg >> 14;
        *(u16x4*)(rowsPad + (b * PADR + (hh + 1) * 130 + (w + 1)) * 256 +
                  h * 64 + e * 4) = ov;
#pragma unroll
        for (int k = 0; k < 4; ++k) {
          int c = h * 64 + e * 4 + k;
          fimgb[((b * 256 + c) * 128 + hh) * 128 + w] = (short)ov[k];
        }
      }
    }
  }
}

// ---------- conv3x3: tiled 9-tap GEMM + BN + ReLU + residual ----------------
__global__ __launch_bounds__(256) void conv_tile(
    const short* __restrict__ cwt, const short* __restrict__ rowsPad,
    const short* __restrict__ fimgb, const float* __restrict__ bnp,
    const int* __restrict__ flag, void* __restrict__ outp) {
  __shared__ short lds[16384];
  const int bf = *flag;
  const int t = threadIdx.x;
  const int l = t & 63, wv = t >> 6;
  const int pb = blockIdx.x;          // 0..255: (batch, image row)
  const int bb = pb >> 7, h = pb & 127;
  const int m0 = blockIdx.y * 128;    // cout base
  const int r = l & 15, q = l >> 4;
  const int wm = wv & 1, wn = wv >> 1;

  f32x4 acc[4][4];
#pragma unroll
  for (int a = 0; a < 4; ++a)
#pragma unroll
    for (int c = 0; c < 4; ++c) acc[a][c] = (f32x4){0.f, 0.f, 0.f, 0.f};

  for (int tap = 0; tap < 9; ++tap) {
    const int ty = tap / 3, tx = tap - ty * 3;
    const int prow0 = bb * PADR + (h + ty) * 130 + tx;
    const short* Abase = cwt + tap * 65536;
    for (int kt = 0; kt < 4; ++kt) {
      const int k0 = kt * 64;
      if (tap | kt) __syncthreads();
#pragma unroll
      for (int j = 0; j < 4; ++j) {
        int flat = (j * 4 + wv) * 64 + l;
        int row = flat >> 3;
        int cs = (flat & 7) ^ (row & 7);
        gload_lds16(Abase + (m0 + row) * 256 + k0 + cs * 8,
                    lds + (j * 4 + wv) * 512);
        gload_lds16(rowsPad + (prow0 + row) * 256 + k0 + cs * 8,
                    lds + 8192 + (j * 4 + wv) * 512);
      }
      __syncthreads();
      bf16x8 af[2][4], bfr[2][4];
#pragma unroll
      for (int kh = 0; kh < 2; ++kh) {
#pragma unroll
        for (int a = 0; a < 4; ++a) {
          int R = wm * 64 + a * 16 + r;
          int s = (kh * 4 + q) ^ (R & 7);
          af[kh][a] = *(const bf16x8*)(lds + R * 64 + s * 8);
        }
#pragma unroll
        for (int c = 0; c < 4; ++c) {
          int R = wn * 64 + c * 16 + r;
          int s = (kh * 4 + q) ^ (R & 7);
          bfr[kh][c] = *(const bf16x8*)(lds + 8192 + R * 64 + s * 8);
        }
      }
#pragma unroll
      for (int kh = 0; kh < 2; ++kh)
#pragma unroll
        for (int a = 0; a < 4; ++a)
#pragma unroll
          for (int c = 0; c < 4; ++c)
            acc[a][c] = __builtin_amdgcn_mfma_f32_16x16x32_bf16(
                af[kh][a], bfr[kh][c], acc[a][c], 0, 0, 0);
    }
  }
#pragma unroll
  for (int c = 0; c < 4; ++c) {
    int w = wn * 64 + c * 16 + r;
#pragma unroll
    for (int a = 0; a < 4; ++a)
#pragma unroll
      for (int i = 0; i < 4; ++i) {
        int m = m0 + wm * 64 + a * 16 + q * 4 + i;   // cout
        float scale = rsqrtf(bnp[768 + m] + 1e-5f) * bnp[m];
        float v = (acc[a][c][i] - bnp[512 + m]) * scale + bnp[256 + m];
        v = fmaxf(v, 0.f);
        int idx = ((bb * 256 + m) * 128 + h) * 128 + w;
        float res = v + b2f(fimgb[idx]);
        if (bf) ((short*)outp)[idx] = f2b(res);
        else    ((float*)outp)[idx] = res;
      }
  }
}

extern "C" void kernel_launch(void* const* d_in, const int* in_sizes, int n_in,
                              void* d_out, int out_size, void* d_ws, size_t ws_size,
                              hipStream_t stream) {
  // Adaptive chunking: pick smallest NCH whose footprint fits ws_size.
  const long long baseS = 18033680LL;
  int NCH = 8;
  for (int cand = 1; cand <= 8; cand <<= 1) {
    long long tot = (baseS + (32768LL / cand) * 3072LL) * 2LL;
    if (tot <= (long long)ws_size) { NCH = cand; break; }
  }
  const int CPIX = 32768 / NCH;

  short* ws = (short*)d_ws;
  short* FROWSP = ws;                        // 8,652,800
  short* FIMG   = ws + 8652800;              // 8,388,608
  short* WT     = ws + 17041408;             // 393,216
  short* CWT    = ws + 17434624;             // 589,824
  float* PB     = (float*)(ws + 18024448);   // 18x256 fp32 (9,216 shorts)
  int*   FLAG   = (int*)(ws + 18033664);     // 16 shorts
  short* XLRc   = ws + 18033680;             // CPIX*2048
  short* Xc     = XLRc + (long long)CPIX * 2048;  // CPIX*1024
  short* MEANc  = XLRc;                      // alias (dead before proj writes)
  short* H1c    = XLRc + (long long)CPIX * 256;   // alias

  detect_dtype<<<1, 256, 0, stream>>>(d_in[3], FLAG);

  P18 pp;
  pp.p[0] = d_in[4];   pp.p[1] = d_in[6];   // fn_b1, fn_b2
  pp.p[2] = d_in[8];   pp.p[3] = d_in[10];  // l0_bl, l0_br
  pp.p[4] = d_in[11];  pp.p[5] = d_in[12];  // l0_att, l0_bias
  pp.p[6] = d_in[13];  pp.p[7] = d_in[14];  // ln0_g, ln0_b
  pp.p[8] = d_in[16];  pp.p[9] = d_in[18];  // l1_bl, l1_br
  pp.p[10] = d_in[19]; pp.p[11] = d_in[20]; // l1_att, l1_bias
  pp.p[12] = d_in[21]; pp.p[13] = d_in[22]; // ln1_g, ln1_b
  pp.p[14] = d_in[24]; pp.p[15] = d_in[25]; // bn_g, bn_b
  pp.p[16] = d_in[26]; pp.p[17] = d_in[27]; // bn_m, bn_v
  prep_params<<<1, 256, 0, stream>>>(pp, FLAG, PB);

  prep_gemm_w<<<dim3(256, 6), 256, 0, stream>>>(d_in[3], d_in[5], d_in[7],
                                                d_in[9], d_in[15], d_in[17],
                                                FLAG, WT);
  prep_conv_w<<<2304, 256, 0, stream>>>(d_in[23], FLAG, CWT);
  zero_border<<<1032, 256, 0, stream>>>(FROWSP);

  for (int ci = 0; ci < NCH; ++ci) {
    gather_chunk<<<CPIX / 64, 256, 0, stream>>>(d_in[0], d_in[1], d_in[2],
                                                FLAG, Xc, MEANc,
                                                ci * (CPIX / 64));
    // fusion MLP: MEANc -> H1c -> Xc node 0
    gemm_tile<1><<<dim3(CPIX / 128, 2), 256, 0, stream>>>(
        MEANc, WT + 0 * 65536, PB + 0 * 256, H1c, 256);
    gemm_tile<0><<<dim3(CPIX / 128, 2), 256, 0, stream>>>(
        H1c, WT + 1 * 65536, PB + 1 * 256, Xc, 1024);
    for (int lyr = 0; lyr < 2; ++lyr) {
      // fused [Wl|Wr] projection: N=512
      gemm_tile<0><<<dim3(4 * CPIX / 128, 4), 256, 0, stream>>>(
          Xc, WT + (2 + 2 * lyr) * 65536, PB + (2 + 6 * lyr) * 256, XLRc, 512);
      attn_ln<<<CPIX / 16, 256, 0, stream>>>(
          XLRc, PB + (4 + 6 * lyr) * 256, PB + (5 + 6 * lyr) * 256,
          PB + (6 + 6 * lyr) * 256, PB + (7 + 6 * lyr) * 256, Xc, ci * CPIX,
          FROWSP, FIMG, lyr);
    }
  }

  conv_tile<<<dim3(256, 2), 256, 0, stream>>>(CWT, FROWSP, FIMG, PB + 14 * 256,
                                              FLAG, d_out);
}

// Round 7
// 704.738 us; speedup vs baseline: 3.4214x; 1.1298x over previous
//
#include <hip/hip_runtime.h>

// GNNRoIFusion on MI355X (gfx950).
// B=2, H=W=128, C=256, HEADS=4, D=64, M=3, P=32768 pixels.
// Round 7: gather_chunk rewritten as vectorized tiled transpose (16B loads,
// LDS tile, 16B coalesced stores, 2048 blocks). All else identical to r6.

#define Pn 32768
#define PADR 16900  // 130*130 padded rows per batch

typedef __attribute__((ext_vector_type(8))) short bf16x8;
typedef __attribute__((ext_vector_type(4))) float f32x4;
typedef __attribute__((ext_vector_type(4))) unsigned short u16x4;
typedef __attribute__((ext_vector_type(8))) unsigned short u16x8;

__device__ __forceinline__ float b2f(short s) {
  unsigned u = ((unsigned)(unsigned short)s) << 16;
  float f;
  __builtin_memcpy(&f, &u, 4);
  return f;
}
__device__ __forceinline__ short f2b(float f) {
  unsigned u;
  __builtin_memcpy(&u, &f, 4);
  u += 0x7fffu + ((u >> 16) & 1u);   // RNE to bf16
  return (short)(u >> 16);
}
__device__ __forceinline__ float ldany(const void* p, int i, int bf) {
  return bf ? b2f(((const short*)p)[i]) : ((const float*)p)[i];
}
// async global->LDS, 16B per lane; lds base wave-uniform, lane i -> base+16i
__device__ __forceinline__ void gload_lds16(const short* g, short* l) {
  __builtin_amdgcn_global_load_lds(
      (const __attribute__((address_space(1))) unsigned int*)g,
      (__attribute__((address_space(3))) unsigned int*)l, 16, 0, 0);
}

// ---------- dtype probe ------------------------------------------------------
__global__ __launch_bounds__(256) void detect_dtype(const void* probe, int* flag) {
  const short* s = (const short*)probe;
  int cnt = 0;
#pragma unroll
  for (int i = 0; i < 8; ++i) {
    short v = s[(threadIdx.x * 8 + i) * 2];
    int e = ((unsigned short)v >> 7) & 0xFF;
    cnt += (e >= 100 && e <= 127) ? 1 : 0;
  }
  __shared__ int tot;
  if (threadIdx.x == 0) tot = 0;
  __syncthreads();
  atomicAdd(&tot, cnt);
  __syncthreads();
  if (threadIdx.x == 0) flag[0] = (tot > 1024) ? 1 : 0;  // 1 = bf16 inputs
}

// ---------- small params -> fp32 block (18 vectors of 256) ------------------
struct P18 { const void* p[18]; };
__global__ __launch_bounds__(256) void prep_params(P18 s, const int* flag, float* pb) {
  int bf = *flag;
  int t = threadIdx.x;
#pragma unroll
  for (int v = 0; v < 18; ++v) pb[v * 256 + t] = ldany(s.p[v], t, bf);
}

// ---------- weight prep: Wt[n][k] = W[k][n] (bf16) --------------------------
__global__ __launch_bounds__(256) void prep_gemm_w(
    const void* w0, const void* w1, const void* w2, const void* w3,
    const void* w4, const void* w5, const int* flag, short* wt) {
  int bf = *flag;
  const void* src;
  switch (blockIdx.y) {
    case 0: src = w0; break;
    case 1: src = w1; break;
    case 2: src = w2; break;
    case 3: src = w3; break;
    case 4: src = w4; break;
    default: src = w5; break;
  }
  int idx = blockIdx.x * 256 + threadIdx.x;     // n*256 + k
  int n = idx >> 8, k = idx & 255;
  wt[blockIdx.y * 65536 + idx] = f2b(ldany(src, k * 256 + n, bf));
}

// conv_w [cout][cin][3][3] -> cwt[tap][cout][cin]
__global__ __launch_bounds__(256) void prep_conv_w(const void* cw, const int* flag,
                                                   short* cwt) {
  int bf = *flag;
  int idx = blockIdx.x * 256 + threadIdx.x;
  int tap = idx >> 16;
  int n = (idx >> 8) & 255;
  int k = idx & 255;
  cwt[idx] = f2b(ldany(cw, (n * 256 + k) * 9 + tap, bf));
}

// ---------- zero the halo of FROWSpad [2][130][130][256] --------------------
__global__ __launch_bounds__(256) void zero_border(short* rowsPad) {
  int id = blockIdx.x;              // 0..1031
  int b = id >= 516;
  int r = id - b * 516;
  int hp, wp;
  if (r < 130)      { hp = 0;       wp = r; }
  else if (r < 260) { hp = 129;     wp = r - 130; }
  else if (r < 388) { hp = r - 259; wp = 0; }
  else              { hp = r - 387; wp = 129; }
  rowsPad[(b * PADR + hp * 130 + wp) * 256 + threadIdx.x] = 0;
}

// ---------- gather: vectorized tiled transpose + mean -----------------------
// grid = (CPIX/64)*4 blocks: seg = bx>>2 (64-pixel segment), cb = (bx&3)*64.
// Load: 16B vectors along w -> LDS tile[3][64c][72]; store: 16B vectors
// along c for X nodes 1..3 + fp32 mean -> meanc.
__global__ __launch_bounds__(256) void gather_chunk(
    const void* m0, const void* m1, const void* m2, const int* flag,
    short* Xc, short* meanc, int sb0) {
  const int bf = *flag;
  const int bx = blockIdx.x;
  const int seg = bx >> 2;
  const int cb = (bx & 3) * 64;
  const int sb = sb0 + seg;
  const int wt = sb & 1, h = (sb >> 1) & 127, b = sb >> 8;
  const int w0 = wt * 64;
  const int lp0 = seg * 64;
  const int t = threadIdx.x;

  __shared__ short tile[3][64][72];   // [m][c][w(+8 pad)], rows 16B-aligned
  const void* srcs[3] = {m0, m1, m2};

  // load phase: 2 passes x 3 modalities; 8 lanes cover one 128B c-row chunk
  const int lsub = t & 7;             // w chunk: lsub*8 .. +8
#pragma unroll
  for (int pass = 0; pass < 2; ++pass) {
    int c_l = pass * 32 + (t >> 3);
    long long gbase = ((long long)(b * 256 + cb + c_l) * 128 + h) * 128 + w0 + lsub * 8;
#pragma unroll
    for (int m = 0; m < 3; ++m) {
      u16x8 v;
      if (bf) {
        v = *(const u16x8*)((const short*)srcs[m] + gbase);
      } else {
        const float* gp = (const float*)srcs[m] + gbase;
        f32x4 f0 = *(const f32x4*)gp;
        f32x4 f1 = *(const f32x4*)(gp + 4);
#pragma unroll
        for (int k = 0; k < 4; ++k) {
          v[k] = (unsigned short)f2b(f0[k]);
          v[4 + k] = (unsigned short)f2b(f1[k]);
        }
      }
      *(u16x8*)&tile[m][c_l][lsub * 8] = v;
    }
  }
  __syncthreads();

  // store phase: 2 passes; 8 lanes cover one 128B c-chunk of an output row
  const int c0 = (t & 7) * 8;
#pragma unroll
  for (int pass = 0; pass < 2; ++pass) {
    int w_l = pass * 32 + (t >> 3);
    float mv[8];
#pragma unroll
    for (int m = 0; m < 3; ++m) {
      u16x8 v;
#pragma unroll
      for (int k = 0; k < 8; ++k) {
        short s = tile[m][c0 + k][w_l];
        v[k] = (unsigned short)s;
        float f = b2f(s);
        mv[k] = (m == 0) ? f : mv[k] + f;
      }
      *(u16x8*)(Xc + (long long)((lp0 + w_l) * 4 + 1 + m) * 256 + cb + c0) = v;
    }
    u16x8 mb;
#pragma unroll
    for (int k = 0; k < 8; ++k)
      mb[k] = (unsigned short)f2b(mv[k] * (1.f / 3.f));
    *(u16x8*)(meanc + (long long)(lp0 + w_l) * 256 + cb + c0) = mb;
  }
}

// ---------- tiled GEMM: out[m*ostride+n] = A[M,256] @ Bt[n][256]^T + bias ---
template <int RELU>
__global__ __launch_bounds__(256) void gemm_tile(
    const short* __restrict__ A, const short* __restrict__ Bt,
    const float* __restrict__ bias, short* __restrict__ out, int ostride) {
  __shared__ short lds[16384];       // A tile [0,8192), B tile [8192,16384)
  const int t = threadIdx.x;
  const int l = t & 63, wv = t >> 6;
  const int m0 = blockIdx.x * 128;
  const int n0 = blockIdx.y * 128;
  const int r = l & 15, q = l >> 4;
  const int wm = wv & 1, wn = wv >> 1;

  f32x4 acc[4][4];
#pragma unroll
  for (int a = 0; a < 4; ++a)
#pragma unroll
    for (int c = 0; c < 4; ++c) acc[a][c] = (f32x4){0.f, 0.f, 0.f, 0.f};

  for (int kt = 0; kt < 4; ++kt) {
    const int k0 = kt * 64;
    if (kt) __syncthreads();
#pragma unroll
    for (int j = 0; j < 4; ++j) {
      int flat = (j * 4 + wv) * 64 + l;
      int row = flat >> 3;
      int cs = (flat & 7) ^ (row & 7);
      gload_lds16(A + (m0 + row) * 256 + k0 + cs * 8, lds + (j * 4 + wv) * 512);
      gload_lds16(Bt + (n0 + row) * 256 + k0 + cs * 8,
                  lds + 8192 + (j * 4 + wv) * 512);
    }
    __syncthreads();
    bf16x8 af[2][4], bfr[2][4];
#pragma unroll
    for (int kh = 0; kh < 2; ++kh) {
#pragma unroll
      for (int a = 0; a < 4; ++a) {
        int R = wm * 64 + a * 16 + r;
        int s = (kh * 4 + q) ^ (R & 7);
        af[kh][a] = *(const bf16x8*)(lds + R * 64 + s * 8);
      }
#pragma unroll
      for (int c = 0; c < 4; ++c) {
        int R = wn * 64 + c * 16 + r;
        int s = (kh * 4 + q) ^ (R & 7);
        bfr[kh][c] = *(const bf16x8*)(lds + 8192 + R * 64 + s * 8);
      }
    }
#pragma unroll
    for (int kh = 0; kh < 2; ++kh)
#pragma unroll
      for (int a = 0; a < 4; ++a)
#pragma unroll
        for (int c = 0; c < 4; ++c)
          acc[a][c] = __builtin_amdgcn_mfma_f32_16x16x32_bf16(
              af[kh][a], bfr[kh][c], acc[a][c], 0, 0, 0);
  }
#pragma unroll
  for (int c = 0; c < 4; ++c) {
    int n = n0 + wn * 64 + c * 16 + r;
    float bs = bias[n];
#pragma unroll
    for (int a = 0; a < 4; ++a)
#pragma unroll
      for (int i = 0; i < 4; ++i) {
        int m = m0 + wm * 64 + a * 16 + q * 4 + i;
        float v = acc[a][c][i] + bs;
        if (RELU) v = fmaxf(v, 0.f);
        out[m * ostride + n] = f2b(v);
      }
  }
}

// ---------- per-pixel GATv2 + residual + layernorm --------------------------
// 4 pixels per wave: lane = p*16 + e; lane covers d = e*4..e*4+3 per head.
__global__ __launch_bounds__(256) void attn_ln(
    const short* __restrict__ XLRc,
    const float* __restrict__ att, const float* __restrict__ bias,
    const float* __restrict__ lng, const float* __restrict__ lnb,
    short* __restrict__ Xc, int pOff, short* rowsPad, short* fimgb,
    int writeFused) {
  const int lane = threadIdx.x & 63;
  const int wv = threadIdx.x >> 6;
  const int e = lane & 15;                       // d-quarter
  const int lp = blockIdx.x * 16 + wv * 4 + (lane >> 4);
  const int pg = pOff + lp;

  float out[4][4][4];    // [i][h][k]
#pragma unroll
  for (int h = 0; h < 4; ++h) {
    float av[4];
#pragma unroll
    for (int k = 0; k < 4; ++k) av[k] = att[h * 64 + e * 4 + k];
    float xlf[4][4], xrf[4][4];
#pragma unroll
    for (int j = 0; j < 4; ++j) {
      const short* rb = XLRc + (lp * 4 + j) * 512 + h * 64 + e * 4;
      u16x4 xlv = *(const u16x4*)rb;
      u16x4 xrv = *(const u16x4*)(rb + 256);
#pragma unroll
      for (int k = 0; k < 4; ++k) {
        xlf[j][k] = b2f((short)xlv[k]);
        xrf[j][k] = b2f((short)xrv[k]);
      }
    }
#pragma unroll
    for (int i = 0; i < 4; ++i) {
      float s[4];
#pragma unroll
      for (int j = 0; j < 4; ++j) {
        float a = 0.f;
#pragma unroll
        for (int k = 0; k < 4; ++k) {
          float t = xrf[i][k] + xlf[j][k];
          t = fmaxf(t, 0.f) + 0.2f * fminf(t, 0.f);   // leaky_relu 0.2
          a += t * av[k];
        }
        a += __shfl_xor(a, 1, 64);
        a += __shfl_xor(a, 2, 64);
        a += __shfl_xor(a, 4, 64);
        a += __shfl_xor(a, 8, 64);
        s[j] = a;
      }
      float mx = fmaxf(fmaxf(s[0], s[1]), fmaxf(s[2], s[3]));
      float e0 = expf(s[0] - mx), e1 = expf(s[1] - mx);
      float e2 = expf(s[2] - mx), e3 = expf(s[3] - mx);
      float inv = 1.f / (e0 + e1 + e2 + e3);
#pragma unroll
      for (int k = 0; k < 4; ++k)
        out[i][h][k] =
            (e0 * xlf[0][k] + e1 * xlf[1][k] + e2 * xlf[2][k] + e3 * xlf[3][k]) * inv;
    }
  }

  float biasf[4][4];
#pragma unroll
  for (int h = 0; h < 4; ++h)
#pragma unroll
    for (int k = 0; k < 4; ++k) biasf[h][k] = bias[h * 64 + e * 4 + k];

#pragma unroll
  for (int i = 0; i < 4; ++i) {
    float y[4][4], sm = 0.f;
#pragma unroll
    for (int h = 0; h < 4; ++h) {
      u16x4 rv = *(const u16x4*)(Xc + (lp * 4 + i) * 256 + h * 64 + e * 4);
#pragma unroll
      for (int k = 0; k < 4; ++k) {
        y[h][k] = out[i][h][k] + biasf[h][k] + b2f((short)rv[k]);
        sm += y[h][k];
      }
    }
    sm += __shfl_xor(sm, 1, 64);
    sm += __shfl_xor(sm, 2, 64);
    sm += __shfl_xor(sm, 4, 64);
    sm += __shfl_xor(sm, 8, 64);
    float mu = sm * (1.f / 256.f);
    float vs = 0.f;
#pragma unroll
    for (int h = 0; h < 4; ++h)
#pragma unroll
      for (int k = 0; k < 4; ++k) {
        float d = y[h][k] - mu;
        vs += d * d;
      }
    vs += __shfl_xor(vs, 1, 64);
    vs += __shfl_xor(vs, 2, 64);
    vs += __shfl_xor(vs, 4, 64);
    vs += __shfl_xor(vs, 8, 64);
    float rs = rsqrtf(vs * (1.f / 256.f) + 1e-5f);
#pragma unroll
    for (int h = 0; h < 4; ++h) {
      float g0 = lng[h * 64 + e * 4 + 0], g1 = lng[h * 64 + e * 4 + 1];
      float g2 = lng[h * 64 + e * 4 + 2], g3 = lng[h * 64 + e * 4 + 3];
      float b0 = lnb[h * 64 + e * 4 + 0], b1 = lnb[h * 64 + e * 4 + 1];
      float b2 = lnb[h * 64 + e * 4 + 2], b3 = lnb[h * 64 + e * 4 + 3];
      u16x4 ov;
      ov[0] = (unsigned short)f2b((y[h][0] - mu) * rs * g0 + b0);
      ov[1] = (unsigned short)f2b((y[h][1] - mu) * rs * g1 + b1);
      ov[2] = (unsigned short)f2b((y[h][2] - mu) * rs * g2 + b2);
      ov[3] = (unsigned short)f2b((y[h][3] - mu) * rs * g3 + b3);
      *(u16x4*)(Xc + (lp * 4 + i) * 256 + h * 64 + e * 4) = ov;
      if (writeFused && i == 0) {
        int w = pg & 127, hh = (pg >> 7) & 127, b = pg >> 14;
        *(u16x4*)(rowsPad + (b * PADR + (hh + 1) * 130 + (w + 1)) * 256 +
                  h * 64 + e * 4) = ov;
#pragma unroll
        for (int k = 0; k < 4; ++k) {
          int c = h * 64 + e * 4 + k;
          fimgb[((b * 256 + c) * 128 + hh) * 128 + w] = (short)ov[k];
        }
      }
    }
  }
}

// ---------- conv3x3: tiled 9-tap GEMM + BN + ReLU + residual ----------------
__global__ __launch_bounds__(256) void conv_tile(
    const short* __restrict__ cwt, const short* __restrict__ rowsPad,
    const short* __restrict__ fimgb, const float* __restrict__ bnp,
    const int* __restrict__ flag, void* __restrict__ outp) {
  __shared__ short lds[16384];
  const int bf = *flag;
  const int t = threadIdx.x;
  const int l = t & 63, wv = t >> 6;
  const int pb = blockIdx.x;          // 0..255: (batch, image row)
  const int bb = pb >> 7, h = pb & 127;
  const int m0 = blockIdx.y * 128;    // cout base
  const int r = l & 15, q = l >> 4;
  const int wm = wv & 1, wn = wv >> 1;

  f32x4 acc[4][4];
#pragma unroll
  for (int a = 0; a < 4; ++a)
#pragma unroll
    for (int c = 0; c < 4; ++c) acc[a][c] = (f32x4){0.f, 0.f, 0.f, 0.f};

  for (int tap = 0; tap < 9; ++tap) {
    const int ty = tap / 3, tx = tap - ty * 3;
    const int prow0 = bb * PADR + (h + ty) * 130 + tx;
    const short* Abase = cwt + tap * 65536;
    for (int kt = 0; kt < 4; ++kt) {
      const int k0 = kt * 64;
      if (tap | kt) __syncthreads();
#pragma unroll
      for (int j = 0; j < 4; ++j) {
        int flat = (j * 4 + wv) * 64 + l;
        int row = flat >> 3;
        int cs = (flat & 7) ^ (row & 7);
        gload_lds16(Abase + (m0 + row) * 256 + k0 + cs * 8,
                    lds + (j * 4 + wv) * 512);
        gload_lds16(rowsPad + (prow0 + row) * 256 + k0 + cs * 8,
                    lds + 8192 + (j * 4 + wv) * 512);
      }
      __syncthreads();
      bf16x8 af[2][4], bfr[2][4];
#pragma unroll
      for (int kh = 0; kh < 2; ++kh) {
#pragma unroll
        for (int a = 0; a < 4; ++a) {
          int R = wm * 64 + a * 16 + r;
          int s = (kh * 4 + q) ^ (R & 7);
          af[kh][a] = *(const bf16x8*)(lds + R * 64 + s * 8);
        }
#pragma unroll
        for (int c = 0; c < 4; ++c) {
          int R = wn * 64 + c * 16 + r;
          int s = (kh * 4 + q) ^ (R & 7);
          bfr[kh][c] = *(const bf16x8*)(lds + 8192 + R * 64 + s * 8);
        }
      }
#pragma unroll
      for (int kh = 0; kh < 2; ++kh)
#pragma unroll
        for (int a = 0; a < 4; ++a)
#pragma unroll
          for (int c = 0; c < 4; ++c)
            acc[a][c] = __builtin_amdgcn_mfma_f32_16x16x32_bf16(
                af[kh][a], bfr[kh][c], acc[a][c], 0, 0, 0);
    }
  }
#pragma unroll
  for (int c = 0; c < 4; ++c) {
    int w = wn * 64 + c * 16 + r;
#pragma unroll
    for (int a = 0; a < 4; ++a)
#pragma unroll
      for (int i = 0; i < 4; ++i) {
        int m = m0 + wm * 64 + a * 16 + q * 4 + i;   // cout
        float scale = rsqrtf(bnp[768 + m] + 1e-5f) * bnp[m];
        float v = (acc[a][c][i] - bnp[512 + m]) * scale + bnp[256 + m];
        v = fmaxf(v, 0.f);
        int idx = ((bb * 256 + m) * 128 + h) * 128 + w;
        float res = v + b2f(fimgb[idx]);
        if (bf) ((short*)outp)[idx] = f2b(res);
        else    ((float*)outp)[idx] = res;
      }
  }
}

extern "C" void kernel_launch(void* const* d_in, const int* in_sizes, int n_in,
                              void* d_out, int out_size, void* d_ws, size_t ws_size,
                              hipStream_t stream) {
  // Adaptive chunking: pick smallest NCH whose footprint fits ws_size.
  const long long baseS = 18033680LL;
  int NCH = 8;
  for (int cand = 1; cand <= 8; cand <<= 1) {
    long long tot = (baseS + (32768LL / cand) * 3072LL) * 2LL;
    if (tot <= (long long)ws_size) { NCH = cand; break; }
  }
  const int CPIX = 32768 / NCH;

  short* ws = (short*)d_ws;
  short* FROWSP = ws;                        // 8,652,800
  short* FIMG   = ws + 8652800;              // 8,388,608
  short* WT     = ws + 17041408;             // 393,216
  short* CWT    = ws + 17434624;             // 589,824
  float* PB     = (float*)(ws + 18024448);   // 18x256 fp32 (9,216 shorts)
  int*   FLAG   = (int*)(ws + 18033664);     // 16 shorts
  short* XLRc   = ws + 18033680;             // CPIX*2048
  short* Xc     = XLRc + (long long)CPIX * 2048;  // CPIX*1024
  short* MEANc  = XLRc;                      // alias (dead before proj writes)
  short* H1c    = XLRc + (long long)CPIX * 256;   // alias

  detect_dtype<<<1, 256, 0, stream>>>(d_in[3], FLAG);

  P18 pp;
  pp.p[0] = d_in[4];   pp.p[1] = d_in[6];   // fn_b1, fn_b2
  pp.p[2] = d_in[8];   pp.p[3] = d_in[10];  // l0_bl, l0_br
  pp.p[4] = d_in[11];  pp.p[5] = d_in[12];  // l0_att, l0_bias
  pp.p[6] = d_in[13];  pp.p[7] = d_in[14];  // ln0_g, ln0_b
  pp.p[8] = d_in[16];  pp.p[9] = d_in[18];  // l1_bl, l1_br
  pp.p[10] = d_in[19]; pp.p[11] = d_in[20]; // l1_att, l1_bias
  pp.p[12] = d_in[21]; pp.p[13] = d_in[22]; // ln1_g, ln1_b
  pp.p[14] = d_in[24]; pp.p[15] = d_in[25]; // bn_g, bn_b
  pp.p[16] = d_in[26]; pp.p[17] = d_in[27]; // bn_m, bn_v
  prep_params<<<1, 256, 0, stream>>>(pp, FLAG, PB);

  prep_gemm_w<<<dim3(256, 6), 256, 0, stream>>>(d_in[3], d_in[5], d_in[7],
                                                d_in[9], d_in[15], d_in[17],
                                                FLAG, WT);
  prep_conv_w<<<2304, 256, 0, stream>>>(d_in[23], FLAG, CWT);
  zero_border<<<1032, 256, 0, stream>>>(FROWSP);

  for (int ci = 0; ci < NCH; ++ci) {
    gather_chunk<<<(CPIX / 64) * 4, 256, 0, stream>>>(d_in[0], d_in[1], d_in[2],
                                                      FLAG, Xc, MEANc,
                                                      ci * (CPIX / 64));
    // fusion MLP: MEANc -> H1c -> Xc node 0
    gemm_tile<1><<<dim3(CPIX / 128, 2), 256, 0, stream>>>(
        MEANc, WT + 0 * 65536, PB + 0 * 256, H1c, 256);
    gemm_tile<0><<<dim3(CPIX / 128, 2), 256, 0, stream>>>(
        H1c, WT + 1 * 65536, PB + 1 * 256, Xc, 1024);
    for (int lyr = 0; lyr < 2; ++lyr) {
      // fused [Wl|Wr] projection: N=512
      gemm_tile<0><<<dim3(4 * CPIX / 128, 4), 256, 0, stream>>>(
          Xc, WT + (2 + 2 * lyr) * 65536, PB + (2 + 6 * lyr) * 256, XLRc, 512);
      attn_ln<<<CPIX / 16, 256, 0, stream>>>(
          XLRc, PB + (4 + 6 * lyr) * 256, PB + (5 + 6 * lyr) * 256,
          PB + (6 + 6 * lyr) * 256, PB + (7 + 6 * lyr) * 256, Xc, ci * CPIX,
          FROWSP, FIMG, lyr);
    }
  }

  conv_tile<<<dim3(256, 2), 256, 0, stream>>>(CWT, FROWSP, FIMG, PB + 14 * 256,
                                              FLAG, d_out);
}